// Round 1
// baseline (829.140 us; speedup 1.0000x reference)
//
#include <hip/hip_runtime.h>
#include <hip/hip_bf16.h>

#define SQ 2048
#define HH 2048
#define NHEAD 16
#define HD 128
#define QKVW (NHEAD*3*HD)   // 6144

typedef __attribute__((ext_vector_type(8))) short bf16x8;
typedef __attribute__((ext_vector_type(4))) float f32x4;

__device__ inline unsigned short f2bf(float f) {
    union { float f; unsigned u; } x; x.f = f;
    unsigned r = x.u + 0x7FFFu + ((x.u >> 16) & 1u);
    return (unsigned short)(r >> 16);
}

__device__ inline float gelu_f(float x) {
    float x3 = x * (1.f + 0.044715f * x * x);
    return 0.5f * x * (1.f + tanhf(0.79788456f * x3));
}

// ---------------- LayerNorm: fp32 in -> bf16 out ----------------
__global__ __launch_bounds__(256) void ln_kernel(
    const float* __restrict__ in, const float* __restrict__ g,
    const float* __restrict__ b, unsigned short* __restrict__ out)
{
    int row = blockIdx.x;
    int t = threadIdx.x, lane = t & 63, wid = t >> 6;
    const float4* rp = (const float4*)(in + (size_t)row * HH);
    float4 v0 = rp[t], v1 = rp[t + 256];
    float s  = v0.x + v0.y + v0.z + v0.w + v1.x + v1.y + v1.z + v1.w;
    float ss = v0.x*v0.x + v0.y*v0.y + v0.z*v0.z + v0.w*v0.w
             + v1.x*v1.x + v1.y*v1.y + v1.z*v1.z + v1.w*v1.w;
    #pragma unroll
    for (int o = 32; o; o >>= 1) { s += __shfl_down(s, o); ss += __shfl_down(ss, o); }
    __shared__ float r0[4], r1[4];
    if (lane == 0) { r0[wid] = s; r1[wid] = ss; }
    __syncthreads();
    s  = r0[0] + r0[1] + r0[2] + r0[3];
    ss = r1[0] + r1[1] + r1[2] + r1[3];
    float mu = s * (1.f / HH);
    float var = ss * (1.f / HH) - mu * mu;
    float rs = rsqrtf(var + 1e-5f);
    float4 g0 = ((const float4*)g)[t], g1 = ((const float4*)g)[t + 256];
    float4 b0 = ((const float4*)b)[t], b1 = ((const float4*)b)[t + 256];
    ushort4 o0, o1;
    o0.x = f2bf((v0.x - mu) * rs * g0.x + b0.x);
    o0.y = f2bf((v0.y - mu) * rs * g0.y + b0.y);
    o0.z = f2bf((v0.z - mu) * rs * g0.z + b0.z);
    o0.w = f2bf((v0.w - mu) * rs * g0.w + b0.w);
    o1.x = f2bf((v1.x - mu) * rs * g1.x + b1.x);
    o1.y = f2bf((v1.y - mu) * rs * g1.y + b1.y);
    o1.z = f2bf((v1.z - mu) * rs * g1.z + b1.z);
    o1.w = f2bf((v1.w - mu) * rs * g1.w + b1.w);
    ushort4* op = (ushort4*)(out + (size_t)row * HH);
    op[t] = o0; op[t + 256] = o1;
}

// ---------------- GEMM: C[M,N] = A[M,K](bf16) @ B[N,K](fp32->bf16)^T + bias (+res)(+gelu) ----
// 128x128 tile, BK=32, 4 waves (2x2), each wave 64x64 via 4x4 16x16x32 mfma frags.
template<int OUT_BF16, int RES, int GELU_ON>
__global__ __launch_bounds__(256) void gemm_bt(
    const unsigned short* __restrict__ A, const float* __restrict__ B,
    const float* __restrict__ bias, const float* __restrict__ res,
    void* __restrict__ outp, int M, int N, int K)
{
    __shared__ unsigned short As[128][40];   // 80B rows: 16B aligned, 2-way banks
    __shared__ unsigned short Bs[128][40];
    int t = threadIdx.x;
    int lane = t & 63, wid = t >> 6;
    int lo = lane & 15, hi = lane >> 4;
    int wr = wid >> 1, wc = wid & 1;
    int m0 = blockIdx.y * 128, n0 = blockIdx.x * 128;
    int srow = t >> 2, sk = (t & 3) * 8;

    f32x4 acc[4][4] = {};
    const unsigned short* Ab = A + (size_t)m0 * K + sk;
    const float* Bb = B + (size_t)n0 * K + sk;

    for (int k0 = 0; k0 < K; k0 += 32) {
        #pragma unroll
        for (int i = 0; i < 2; i++) {
            int r = srow + i * 64;
            int4 va = *(const int4*)(Ab + (size_t)r * K + k0);
            *(int4*)&As[r][sk] = va;
            const float* bp = Bb + (size_t)r * K + k0;
            float4 f0 = *(const float4*)bp;
            float4 f1 = *(const float4*)(bp + 4);
            ushort4 c0, c1;
            c0.x = f2bf(f0.x); c0.y = f2bf(f0.y); c0.z = f2bf(f0.z); c0.w = f2bf(f0.w);
            c1.x = f2bf(f1.x); c1.y = f2bf(f1.y); c1.z = f2bf(f1.z); c1.w = f2bf(f1.w);
            *(ushort4*)&Bs[r][sk] = c0;
            *(ushort4*)&Bs[r][sk + 4] = c1;
        }
        __syncthreads();
        bf16x8 af[4], bfr[4];
        #pragma unroll
        for (int r = 0; r < 4; r++) af[r]  = *(const bf16x8*)&As[wr * 64 + r * 16 + lo][hi * 8];
        #pragma unroll
        for (int c = 0; c < 4; c++) bfr[c] = *(const bf16x8*)&Bs[wc * 64 + c * 16 + lo][hi * 8];
        #pragma unroll
        for (int r = 0; r < 4; r++)
            #pragma unroll
            for (int c = 0; c < 4; c++)
                acc[r][c] = __builtin_amdgcn_mfma_f32_16x16x32_bf16(af[r], bfr[c], acc[r][c], 0, 0, 0);
        __syncthreads();
    }

    #pragma unroll
    for (int c = 0; c < 4; c++) {
        int gc = n0 + wc * 64 + c * 16 + lo;
        float bi = bias[gc];
        #pragma unroll
        for (int r = 0; r < 4; r++) {
            #pragma unroll
            for (int i = 0; i < 4; i++) {
                int gr = m0 + wr * 64 + r * 16 + hi * 4 + i;
                float v = acc[r][c][i] + bi;
                if (GELU_ON) v = gelu_f(v);
                if (RES) v += res[(size_t)gr * N + gc];
                if (OUT_BF16) ((unsigned short*)outp)[(size_t)gr * N + gc] = f2bf(v);
                else          ((float*)outp)[(size_t)gr * N + gc] = v;
            }
        }
    }
}

// ---------------- Flash attention, causal + alibi ----------------
// Grid (S/64, NH). 4 waves, each owns 16 q-rows. KV blocks of 32.
// Swapped QK^T (A=K,B=Q): lane holds col=q(=lo), rows=kpos -> softmax reduce over hi groups.
// PV computes ctx^T (A=V^T, B=P): acc col=q, rows=d.
__global__ __launch_bounds__(256) void attn_kernel(
    const unsigned short* __restrict__ qkv,   // [S][6144] bf16, (n,t,d) packed
    const float* __restrict__ alibi,          // [NH][S]
    unsigned short* __restrict__ ctx)         // [S][2048] bf16
{
    int n = blockIdx.y, qb = blockIdx.x;
    int t = threadIdx.x, lane = t & 63, wid = t >> 6;
    int lo = lane & 15, hi = lane >> 4;
    int q0 = qb * 64, qw = q0 + wid * 16;
    int qg = qw + lo;

    __shared__ unsigned short Ks[32][136];    // [kpos][d], pad 8
    __shared__ unsigned short Vt[128][40];    // [d][kpos], pad 8
    __shared__ unsigned short Ps[4][16][40];  // per-wave [q][kpos], pad 8

    bf16x8 qf[4];
    #pragma unroll
    for (int dh = 0; dh < 4; dh++)
        qf[dh] = *(const bf16x8*)(qkv + (size_t)qg * QKVW + n * (3 * HD) + dh * 32 + hi * 8);

    const float inv = 0.08838834764831845f;   // 1/sqrt(128)
    float m = -INFINITY, lsum = 0.f;
    f32x4 ao[8] = {};

    int nkb = ((q0 + 63) >> 5) + 1;
    for (int kb = 0; kb < nkb; kb++) {
        int k0 = kb * 32;
        #pragma unroll
        for (int i = 0; i < 2; i++) {
            int idx = i * 256 + t;
            int r = idx >> 4, dg = (idx & 15) * 8;
            const unsigned short* kp = qkv + (size_t)(k0 + r) * QKVW + n * (3 * HD) + HD + dg;
            int4 kv = *(const int4*)kp;
            *(int4*)&Ks[r][dg] = kv;
            int4 vv = *(const int4*)(kp + HD);
            unsigned short tmp[8]; *(int4*)tmp = vv;
            #pragma unroll
            for (int j = 0; j < 8; j++) Vt[dg + j][r] = tmp[j];
        }
        __syncthreads();

        f32x4 sc0 = {}, sc1 = {};
        #pragma unroll
        for (int dh = 0; dh < 4; dh++) {
            bf16x8 k0f = *(const bf16x8*)&Ks[lo][dh * 32 + hi * 8];
            bf16x8 k1f = *(const bf16x8*)&Ks[16 + lo][dh * 32 + hi * 8];
            sc0 = __builtin_amdgcn_mfma_f32_16x16x32_bf16(k0f, qf[dh], sc0, 0, 0, 0);
            sc1 = __builtin_amdgcn_mfma_f32_16x16x32_bf16(k1f, qf[dh], sc1, 0, 0, 0);
        }

        float pv[8]; float tmax = -INFINITY;
        #pragma unroll
        for (int i = 0; i < 4; i++) {
            int kp0 = k0 + hi * 4 + i;
            float s0 = sc0[i] * inv + alibi[n * SQ + kp0];
            if (kp0 > qg) s0 = -INFINITY;
            int kp1 = kp0 + 16;
            float s1 = sc1[i] * inv + alibi[n * SQ + kp1];
            if (kp1 > qg) s1 = -INFINITY;
            pv[i] = s0; pv[4 + i] = s1;
            tmax = fmaxf(tmax, fmaxf(s0, s1));
        }
        tmax = fmaxf(tmax, __shfl_xor(tmax, 16));
        tmax = fmaxf(tmax, __shfl_xor(tmax, 32));
        float mnew = fmaxf(m, tmax);
        float scale = __expf(m - mnew);
        float psum = 0.f;
        #pragma unroll
        for (int i = 0; i < 4; i++) {
            float p0 = __expf(pv[i] - mnew);
            float p1 = __expf(pv[4 + i] - mnew);
            psum += p0 + p1;
            Ps[wid][lo][hi * 4 + i] = f2bf(p0);
            Ps[wid][lo][16 + hi * 4 + i] = f2bf(p1);
        }
        psum += __shfl_xor(psum, 16);
        psum += __shfl_xor(psum, 32);
        lsum = lsum * scale + psum;
        m = mnew;
        #pragma unroll
        for (int dt = 0; dt < 8; dt++) {
            #pragma unroll
            for (int i = 0; i < 4; i++) ao[dt][i] *= scale;
        }
        bf16x8 pf = *(const bf16x8*)&Ps[wid][lo][hi * 8];
        #pragma unroll
        for (int dt = 0; dt < 8; dt++) {
            bf16x8 vf = *(const bf16x8*)&Vt[dt * 16 + lo][hi * 8];
            ao[dt] = __builtin_amdgcn_mfma_f32_16x16x32_bf16(vf, pf, ao[dt], 0, 0, 0);
        }
        __syncthreads();
    }

    float rl = 1.f / lsum;
    #pragma unroll
    for (int dt = 0; dt < 8; dt++) {
        ushort4 o;
        o.x = f2bf(ao[dt][0] * rl); o.y = f2bf(ao[dt][1] * rl);
        o.z = f2bf(ao[dt][2] * rl); o.w = f2bf(ao[dt][3] * rl);
        *(ushort4*)(ctx + (size_t)qg * HH + n * HD + dt * 16 + hi * 4) = o;
    }
}

extern "C" void kernel_launch(void* const* d_in, const int* in_sizes, int n_in,
                              void* d_out, int out_size, void* d_ws, size_t ws_size,
                              hipStream_t stream) {
    const float* hs    = (const float*)d_in[0];
    const float* alibi = (const float*)d_in[2];
    const float* ln1g  = (const float*)d_in[4];
    const float* ln1b  = (const float*)d_in[5];
    const float* qkvw  = (const float*)d_in[6];
    const float* qkvb  = (const float*)d_in[7];
    const float* dw    = (const float*)d_in[8];
    const float* db    = (const float*)d_in[9];
    const float* ln2g  = (const float*)d_in[10];
    const float* ln2b  = (const float*)d_in[11];
    const float* f1w   = (const float*)d_in[12];
    const float* f1b   = (const float*)d_in[13];
    const float* f2w   = (const float*)d_in[14];
    const float* f2b   = (const float*)d_in[15];
    float* out = (float*)d_out;

    char* ws = (char*)d_ws;
    size_t off = 0;
    auto alloc = [&](size_t nbytes) {
        void* p = ws + off; off += (nbytes + 255) & ~(size_t)255; return p;
    };
    unsigned short* xbf  = (unsigned short*)alloc((size_t)SQ * HH * 2);
    unsigned short* qkvB = (unsigned short*)alloc((size_t)SQ * QKVW * 2);
    unsigned short* ctx  = (unsigned short*)alloc((size_t)SQ * HH * 2);
    float*          attn = (float*)alloc((size_t)SQ * HH * 4);
    unsigned short* y    = (unsigned short*)alloc((size_t)SQ * HH * 2);
    unsigned short* hdn  = (unsigned short*)alloc((size_t)SQ * 4 * HH * 2);

    ln_kernel<<<SQ, 256, 0, stream>>>(hs, ln1g, ln1b, xbf);
    gemm_bt<1, 0, 0><<<dim3(QKVW / 128, SQ / 128), 256, 0, stream>>>(
        xbf, qkvw, qkvb, nullptr, qkvB, SQ, QKVW, HH);
    attn_kernel<<<dim3(SQ / 64, NHEAD), 256, 0, stream>>>(qkvB, alibi, ctx);
    gemm_bt<0, 1, 0><<<dim3(HH / 128, SQ / 128), 256, 0, stream>>>(
        ctx, dw, db, hs, attn, SQ, HH, HH);
    ln_kernel<<<SQ, 256, 0, stream>>>(attn, ln2g, ln2b, y);
    gemm_bt<1, 0, 1><<<dim3(4 * HH / 128, SQ / 128), 256, 0, stream>>>(
        y, f1w, f1b, nullptr, hdn, SQ, 4 * HH, HH);
    gemm_bt<0, 1, 0><<<dim3(HH / 128, SQ / 128), 256, 0, stream>>>(
        hdn, f2w, f2b, attn, out, SQ, HH, 4 * HH);
}

// Round 2
// 665.929 us; speedup vs baseline: 1.2451x; 1.2451x over previous
//
#include <hip/hip_runtime.h>
#include <hip/hip_bf16.h>

#define SQ 2048
#define HH 2048
#define NHEAD 16
#define HD 128
#define QKVW (NHEAD*3*HD)   // 6144

typedef __attribute__((ext_vector_type(8))) short bf16x8;
typedef __attribute__((ext_vector_type(4))) float f32x4;

__device__ inline unsigned short f2bf(float f) {
    union { float f; unsigned u; } x; x.f = f;
    unsigned r = x.u + 0x7FFFu + ((x.u >> 16) & 1u);
    return (unsigned short)(r >> 16);
}

__device__ inline float gelu_f(float x) {
    float x3 = x * (1.f + 0.044715f * x * x);
    return 0.5f * x * (1.f + tanhf(0.79788456f * x3));
}

// async global->LDS, 16B per lane. lds must be wave-uniform; g is per-lane.
__device__ inline void gld16(void* lds, const void* g) {
    __builtin_amdgcn_global_load_lds(
        (__attribute__((address_space(1))) void*)(g),
        (__attribute__((address_space(3))) void*)(lds), 16, 0, 0);
}

// ---------------- fp32 -> bf16 convert (grid-stride, float4) ----------------
__global__ __launch_bounds__(256) void cvt_kernel(
    const float* __restrict__ in, unsigned short* __restrict__ out, int n4)
{
    int i = blockIdx.x * blockDim.x + threadIdx.x;
    int stride = gridDim.x * blockDim.x;
    for (; i < n4; i += stride) {
        float4 f = ((const float4*)in)[i];
        ushort4 o;
        o.x = f2bf(f.x); o.y = f2bf(f.y); o.z = f2bf(f.z); o.w = f2bf(f.w);
        ((ushort4*)out)[i] = o;
    }
}

// ---------------- LayerNorm: fp32 in -> bf16 out ----------------
__global__ __launch_bounds__(256) void ln_kernel(
    const float* __restrict__ in, const float* __restrict__ g,
    const float* __restrict__ b, unsigned short* __restrict__ out)
{
    int row = blockIdx.x;
    int t = threadIdx.x, lane = t & 63, wid = t >> 6;
    const float4* rp = (const float4*)(in + (size_t)row * HH);
    float4 v0 = rp[t], v1 = rp[t + 256];
    float s  = v0.x + v0.y + v0.z + v0.w + v1.x + v1.y + v1.z + v1.w;
    float ss = v0.x*v0.x + v0.y*v0.y + v0.z*v0.z + v0.w*v0.w
             + v1.x*v1.x + v1.y*v1.y + v1.z*v1.z + v1.w*v1.w;
    #pragma unroll
    for (int o = 32; o; o >>= 1) { s += __shfl_down(s, o); ss += __shfl_down(ss, o); }
    __shared__ float r0[4], r1[4];
    if (lane == 0) { r0[wid] = s; r1[wid] = ss; }
    __syncthreads();
    s  = r0[0] + r0[1] + r0[2] + r0[3];
    ss = r1[0] + r1[1] + r1[2] + r1[3];
    float mu = s * (1.f / HH);
    float var = ss * (1.f / HH) - mu * mu;
    float rs = rsqrtf(var + 1e-5f);
    float4 g0 = ((const float4*)g)[t], g1 = ((const float4*)g)[t + 256];
    float4 b0 = ((const float4*)b)[t], b1 = ((const float4*)b)[t + 256];
    ushort4 o0, o1;
    o0.x = f2bf((v0.x - mu) * rs * g0.x + b0.x);
    o0.y = f2bf((v0.y - mu) * rs * g0.y + b0.y);
    o0.z = f2bf((v0.z - mu) * rs * g0.z + b0.z);
    o0.w = f2bf((v0.w - mu) * rs * g0.w + b0.w);
    o1.x = f2bf((v1.x - mu) * rs * g1.x + b1.x);
    o1.y = f2bf((v1.y - mu) * rs * g1.y + b1.y);
    o1.z = f2bf((v1.z - mu) * rs * g1.z + b1.z);
    o1.w = f2bf((v1.w - mu) * rs * g1.w + b1.w);
    ushort4* op = (ushort4*)(out + (size_t)row * HH);
    op[t] = o0; op[t + 256] = o1;
}

// ---------------- GEMM (m97 structure): C[M,N] = A[M,K]bf16 @ B[N,K]bf16^T ----
// 128x128 tile, BK=32, 4 waves (2x2), 4x4 16x16x32 frags/wave.
// Staging: global_load_lds width=16, linear [128][32] LDS (64B rows).
template<int OUT_BF16, int RES, int GELU_ON>
__global__ __launch_bounds__(256) void gemm_bt(
    const unsigned short* __restrict__ A, const unsigned short* __restrict__ B,
    const float* __restrict__ bias, const float* __restrict__ res,
    void* __restrict__ outp, int M, int N, int K)
{
    __shared__ __align__(16) unsigned short As[128][32];
    __shared__ __align__(16) unsigned short Bs[128][32];
    int t = threadIdx.x, lane = t & 63, wid = t >> 6;
    int lo = lane & 15, hi = lane >> 4;
    int wr = wid >> 1, wc = wid & 1;
    int m0 = blockIdx.y * 128, n0 = blockIdx.x * 128;

    // wave w stages rows [w*32, w*32+32): lane covers row w*32+i*16+(l>>2), col (l&3)*8
    int srow = wid * 32 + (lane >> 2);
    int scol = (lane & 3) * 8;
    const unsigned short* Ag = A + (size_t)(m0 + srow) * K + scol;
    const unsigned short* Bg = B + (size_t)(n0 + srow) * K + scol;
    unsigned short* la0 = &As[wid * 32][0];
    unsigned short* la1 = &As[wid * 32 + 16][0];
    unsigned short* lb0 = &Bs[wid * 32][0];
    unsigned short* lb1 = &Bs[wid * 32 + 16][0];

    f32x4 acc[4][4] = {};
    for (int k0 = 0; k0 < K; k0 += 32) {
        gld16(la0, Ag + k0);
        gld16(la1, Ag + (size_t)16 * K + k0);
        gld16(lb0, Bg + k0);
        gld16(lb1, Bg + (size_t)16 * K + k0);
        __syncthreads();
        bf16x8 af[4], bfr[4];
        #pragma unroll
        for (int r = 0; r < 4; r++) af[r]  = *(const bf16x8*)&As[wr * 64 + r * 16 + lo][hi * 8];
        #pragma unroll
        for (int c = 0; c < 4; c++) bfr[c] = *(const bf16x8*)&Bs[wc * 64 + c * 16 + lo][hi * 8];
        #pragma unroll
        for (int r = 0; r < 4; r++)
            #pragma unroll
            for (int c = 0; c < 4; c++)
                acc[r][c] = __builtin_amdgcn_mfma_f32_16x16x32_bf16(af[r], bfr[c], acc[r][c], 0, 0, 0);
        __syncthreads();
    }

    #pragma unroll
    for (int c = 0; c < 4; c++) {
        int gc = n0 + wc * 64 + c * 16 + lo;
        float bi = bias[gc];
        #pragma unroll
        for (int r = 0; r < 4; r++) {
            #pragma unroll
            for (int i = 0; i < 4; i++) {
                int gr = m0 + wr * 64 + r * 16 + hi * 4 + i;
                float v = acc[r][c][i] + bi;
                if (GELU_ON) v = gelu_f(v);
                if (RES) v += res[(size_t)gr * N + gc];
                if (OUT_BF16) ((unsigned short*)outp)[(size_t)gr * N + gc] = f2bf(v);
                else          ((float*)outp)[(size_t)gr * N + gc] = v;
            }
        }
    }
}

// ---------------- Flash attention, causal + alibi ----------------
__global__ __launch_bounds__(256) void attn_kernel(
    const unsigned short* __restrict__ qkv,   // [S][6144] bf16, (n,t,d) packed
    const float* __restrict__ alibi,          // [NH][S]
    unsigned short* __restrict__ ctx)         // [S][2048] bf16
{
    int n = blockIdx.y, qb = blockIdx.x;
    int t = threadIdx.x, lane = t & 63, wid = t >> 6;
    int lo = lane & 15, hi = lane >> 4;
    int q0 = qb * 64, qw = q0 + wid * 16;
    int qg = qw + lo;

    __shared__ unsigned short Ks[32][136];
    __shared__ unsigned short Vt[128][40];
    __shared__ unsigned short Ps[4][16][40];

    bf16x8 qf[4];
    #pragma unroll
    for (int dh = 0; dh < 4; dh++)
        qf[dh] = *(const bf16x8*)(qkv + (size_t)qg * QKVW + n * (3 * HD) + dh * 32 + hi * 8);

    const float inv = 0.08838834764831845f;   // 1/sqrt(128)
    float m = -INFINITY, lsum = 0.f;
    f32x4 ao[8] = {};

    int nkb = ((q0 + 63) >> 5) + 1;
    for (int kb = 0; kb < nkb; kb++) {
        int k0 = kb * 32;
        #pragma unroll
        for (int i = 0; i < 2; i++) {
            int idx = i * 256 + t;
            int r = idx >> 4, dg = (idx & 15) * 8;
            const unsigned short* kp = qkv + (size_t)(k0 + r) * QKVW + n * (3 * HD) + HD + dg;
            int4 kv = *(const int4*)kp;
            *(int4*)&Ks[r][dg] = kv;
            int4 vv = *(const int4*)(kp + HD);
            unsigned short tmp[8]; *(int4*)tmp = vv;
            #pragma unroll
            for (int j = 0; j < 8; j++) Vt[dg + j][r] = tmp[j];
        }
        __syncthreads();

        f32x4 sc0 = {}, sc1 = {};
        #pragma unroll
        for (int dh = 0; dh < 4; dh++) {
            bf16x8 k0f = *(const bf16x8*)&Ks[lo][dh * 32 + hi * 8];
            bf16x8 k1f = *(const bf16x8*)&Ks[16 + lo][dh * 32 + hi * 8];
            sc0 = __builtin_amdgcn_mfma_f32_16x16x32_bf16(k0f, qf[dh], sc0, 0, 0, 0);
            sc1 = __builtin_amdgcn_mfma_f32_16x16x32_bf16(k1f, qf[dh], sc1, 0, 0, 0);
        }

        float pv[8]; float tmax = -INFINITY;
        #pragma unroll
        for (int i = 0; i < 4; i++) {
            int kp0 = k0 + hi * 4 + i;
            float s0 = sc0[i] * inv + alibi[n * SQ + kp0];
            if (kp0 > qg) s0 = -INFINITY;
            int kp1 = kp0 + 16;
            float s1 = sc1[i] * inv + alibi[n * SQ + kp1];
            if (kp1 > qg) s1 = -INFINITY;
            pv[i] = s0; pv[4 + i] = s1;
            tmax = fmaxf(tmax, fmaxf(s0, s1));
        }
        tmax = fmaxf(tmax, __shfl_xor(tmax, 16));
        tmax = fmaxf(tmax, __shfl_xor(tmax, 32));
        float mnew = fmaxf(m, tmax);
        float scale = __expf(m - mnew);
        float psum = 0.f;
        #pragma unroll
        for (int i = 0; i < 4; i++) {
            float p0 = __expf(pv[i] - mnew);
            float p1 = __expf(pv[4 + i] - mnew);
            psum += p0 + p1;
            Ps[wid][lo][hi * 4 + i] = f2bf(p0);
            Ps[wid][lo][16 + hi * 4 + i] = f2bf(p1);
        }
        psum += __shfl_xor(psum, 16);
        psum += __shfl_xor(psum, 32);
        lsum = lsum * scale + psum;
        m = mnew;
        #pragma unroll
        for (int dt = 0; dt < 8; dt++) {
            #pragma unroll
            for (int i = 0; i < 4; i++) ao[dt][i] *= scale;
        }
        bf16x8 pf = *(const bf16x8*)&Ps[wid][lo][hi * 8];
        #pragma unroll
        for (int dt = 0; dt < 8; dt++) {
            bf16x8 vf = *(const bf16x8*)&Vt[dt * 16 + lo][hi * 8];
            ao[dt] = __builtin_amdgcn_mfma_f32_16x16x32_bf16(vf, pf, ao[dt], 0, 0, 0);
        }
        __syncthreads();
    }

    float rl = 1.f / lsum;
    #pragma unroll
    for (int dt = 0; dt < 8; dt++) {
        ushort4 o;
        o.x = f2bf(ao[dt][0] * rl); o.y = f2bf(ao[dt][1] * rl);
        o.z = f2bf(ao[dt][2] * rl); o.w = f2bf(ao[dt][3] * rl);
        *(ushort4*)(ctx + (size_t)qg * HH + n * HD + dt * 16 + hi * 4) = o;
    }
}

extern "C" void kernel_launch(void* const* d_in, const int* in_sizes, int n_in,
                              void* d_out, int out_size, void* d_ws, size_t ws_size,
                              hipStream_t stream) {
    const float* hs    = (const float*)d_in[0];
    const float* alibi = (const float*)d_in[2];
    const float* ln1g  = (const float*)d_in[4];
    const float* ln1b  = (const float*)d_in[5];
    const float* qkvw  = (const float*)d_in[6];
    const float* qkvb  = (const float*)d_in[7];
    const float* dw    = (const float*)d_in[8];
    const float* db    = (const float*)d_in[9];
    const float* ln2g  = (const float*)d_in[10];
    const float* ln2b  = (const float*)d_in[11];
    const float* f1w   = (const float*)d_in[12];
    const float* f1b   = (const float*)d_in[13];
    const float* f2w   = (const float*)d_in[14];
    const float* f2b   = (const float*)d_in[15];
    float* out = (float*)d_out;

    char* ws = (char*)d_ws;
    size_t off = 0;
    auto alloc = [&](size_t nbytes) {
        void* p = ws + off; off += (nbytes + 255) & ~(size_t)255; return p;
    };
    unsigned short* xbf  = (unsigned short*)alloc((size_t)SQ * HH * 2);
    unsigned short* qkvB = (unsigned short*)alloc((size_t)SQ * QKVW * 2);
    unsigned short* ctx  = (unsigned short*)alloc((size_t)SQ * HH * 2);
    float*          attn = (float*)alloc((size_t)SQ * HH * 4);
    unsigned short* y    = (unsigned short*)alloc((size_t)SQ * HH * 2);
    unsigned short* hdn  = (unsigned short*)alloc((size_t)SQ * 4 * HH * 2);
    unsigned short* wbuf = (unsigned short*)alloc((size_t)4 * HH * HH * 2); // 33.5MB, reused per GEMM

    ln_kernel<<<SQ, 256, 0, stream>>>(hs, ln1g, ln1b, xbf);

    cvt_kernel<<<2048, 256, 0, stream>>>(qkvw, wbuf, QKVW * HH / 4);
    gemm_bt<1, 0, 0><<<dim3(QKVW / 128, SQ / 128), 256, 0, stream>>>(
        xbf, wbuf, qkvb, nullptr, qkvB, SQ, QKVW, HH);

    attn_kernel<<<dim3(SQ / 64, NHEAD), 256, 0, stream>>>(qkvB, alibi, ctx);

    cvt_kernel<<<1024, 256, 0, stream>>>(dw, wbuf, HH * HH / 4);
    gemm_bt<0, 1, 0><<<dim3(HH / 128, SQ / 128), 256, 0, stream>>>(
        ctx, wbuf, db, hs, attn, SQ, HH, HH);

    ln_kernel<<<SQ, 256, 0, stream>>>(attn, ln2g, ln2b, y);

    cvt_kernel<<<2048, 256, 0, stream>>>(f1w, wbuf, 4 * HH * HH / 4);
    gemm_bt<1, 0, 1><<<dim3(4 * HH / 128, SQ / 128), 256, 0, stream>>>(
        y, wbuf, f1b, nullptr, hdn, SQ, 4 * HH, HH);

    cvt_kernel<<<2048, 256, 0, stream>>>(f2w, wbuf, 4 * HH * HH / 4);
    gemm_bt<0, 1, 0><<<dim3(HH / 128, SQ / 128), 256, 0, stream>>>(
        hdn, wbuf, f2b, attn, out, SQ, HH, 4 * HH);
}

// Round 3
// 593.460 us; speedup vs baseline: 1.3971x; 1.1221x over previous
//
#include <hip/hip_runtime.h>
#include <hip/hip_bf16.h>

#define SQ 2048
#define HH 2048
#define NHEAD 16
#define HD 128
#define QKVW (NHEAD*3*HD)   // 6144

typedef __attribute__((ext_vector_type(8))) short bf16x8;
typedef __attribute__((ext_vector_type(4))) float f32x4;
typedef __attribute__((ext_vector_type(16))) float f32x16;

__device__ inline unsigned short f2bf(float f) {
    union { float f; unsigned u; } x; x.f = f;
    unsigned r = x.u + 0x7FFFu + ((x.u >> 16) & 1u);
    return (unsigned short)(r >> 16);
}

__device__ inline unsigned pack_bf2(float a, float b) {
    return (unsigned)f2bf(a) | ((unsigned)f2bf(b) << 16);
}

__device__ inline float gelu_f(float x) {
    float x3 = x * (1.f + 0.044715f * x * x);
    return 0.5f * x * (1.f + tanhf(0.79788456f * x3));
}

// async global->LDS, 16B per lane. lds must be wave-uniform; g is per-lane.
__device__ inline void gld16(void* lds, const void* g) {
    __builtin_amdgcn_global_load_lds(
        (__attribute__((address_space(1))) void*)(g),
        (__attribute__((address_space(3))) void*)(lds), 16, 0, 0);
}

// ---------------- fp32 -> bf16 convert (grid-stride, float4) ----------------
__global__ __launch_bounds__(256) void cvt_kernel(
    const float* __restrict__ in, unsigned short* __restrict__ out, int n4)
{
    int i = blockIdx.x * blockDim.x + threadIdx.x;
    int stride = gridDim.x * blockDim.x;
    for (; i < n4; i += stride) {
        float4 f = ((const float4*)in)[i];
        ushort4 o;
        o.x = f2bf(f.x); o.y = f2bf(f.y); o.z = f2bf(f.z); o.w = f2bf(f.w);
        ((ushort4*)out)[i] = o;
    }
}

// ---------------- LayerNorm: fp32 in -> bf16 out ----------------
__global__ __launch_bounds__(256) void ln_kernel(
    const float* __restrict__ in, const float* __restrict__ g,
    const float* __restrict__ b, unsigned short* __restrict__ out)
{
    int row = blockIdx.x;
    int t = threadIdx.x, lane = t & 63, wid = t >> 6;
    const float4* rp = (const float4*)(in + (size_t)row * HH);
    float4 v0 = rp[t], v1 = rp[t + 256];
    float s  = v0.x + v0.y + v0.z + v0.w + v1.x + v1.y + v1.z + v1.w;
    float ss = v0.x*v0.x + v0.y*v0.y + v0.z*v0.z + v0.w*v0.w
             + v1.x*v1.x + v1.y*v1.y + v1.z*v1.z + v1.w*v1.w;
    #pragma unroll
    for (int o = 32; o; o >>= 1) { s += __shfl_down(s, o); ss += __shfl_down(ss, o); }
    __shared__ float r0[4], r1[4];
    if (lane == 0) { r0[wid] = s; r1[wid] = ss; }
    __syncthreads();
    s  = r0[0] + r0[1] + r0[2] + r0[3];
    ss = r1[0] + r1[1] + r1[2] + r1[3];
    float mu = s * (1.f / HH);
    float var = ss * (1.f / HH) - mu * mu;
    float rs = rsqrtf(var + 1e-5f);
    float4 g0 = ((const float4*)g)[t], g1 = ((const float4*)g)[t + 256];
    float4 b0 = ((const float4*)b)[t], b1 = ((const float4*)b)[t + 256];
    ushort4 o0, o1;
    o0.x = f2bf((v0.x - mu) * rs * g0.x + b0.x);
    o0.y = f2bf((v0.y - mu) * rs * g0.y + b0.y);
    o0.z = f2bf((v0.z - mu) * rs * g0.z + b0.z);
    o0.w = f2bf((v0.w - mu) * rs * g0.w + b0.w);
    o1.x = f2bf((v1.x - mu) * rs * g1.x + b1.x);
    o1.y = f2bf((v1.y - mu) * rs * g1.y + b1.y);
    o1.z = f2bf((v1.z - mu) * rs * g1.z + b1.z);
    o1.w = f2bf((v1.w - mu) * rs * g1.w + b1.w);
    ushort4* op = (ushort4*)(out + (size_t)row * HH);
    op[t] = o0; op[t + 256] = o1;
}

// ---------------- GEMM (m97 structure): C[M,N] = A[M,K]bf16 @ B[N,K]bf16^T ----
// SPLITV: for the QKV GEMM, v-third columns are written transposed to vtb[n][d][t].
template<int OUT_BF16, int RES, int GELU_ON, int SPLITV>
__global__ __launch_bounds__(256) void gemm_bt(
    const unsigned short* __restrict__ A, const unsigned short* __restrict__ B,
    const float* __restrict__ bias, const float* __restrict__ res,
    void* __restrict__ outp, unsigned short* __restrict__ vtb,
    int M, int N, int K)
{
    __shared__ __align__(16) unsigned short As[128][32];
    __shared__ __align__(16) unsigned short Bs[128][32];
    int t = threadIdx.x, lane = t & 63, wid = t >> 6;
    int lo = lane & 15, hi = lane >> 4;
    int wr = wid >> 1, wc = wid & 1;
    int m0 = blockIdx.y * 128, n0 = blockIdx.x * 128;

    int srow = wid * 32 + (lane >> 2);
    int scol = (lane & 3) * 8;
    const unsigned short* Ag = A + (size_t)(m0 + srow) * K + scol;
    const unsigned short* Bg = B + (size_t)(n0 + srow) * K + scol;
    unsigned short* la0 = &As[wid * 32][0];
    unsigned short* la1 = &As[wid * 32 + 16][0];
    unsigned short* lb0 = &Bs[wid * 32][0];
    unsigned short* lb1 = &Bs[wid * 32 + 16][0];

    f32x4 acc[4][4] = {};
    for (int k0 = 0; k0 < K; k0 += 32) {
        gld16(la0, Ag + k0);
        gld16(la1, Ag + (size_t)16 * K + k0);
        gld16(lb0, Bg + k0);
        gld16(lb1, Bg + (size_t)16 * K + k0);
        __syncthreads();
        bf16x8 af[4], bfr[4];
        #pragma unroll
        for (int r = 0; r < 4; r++) af[r]  = *(const bf16x8*)&As[wr * 64 + r * 16 + lo][hi * 8];
        #pragma unroll
        for (int c = 0; c < 4; c++) bfr[c] = *(const bf16x8*)&Bs[wc * 64 + c * 16 + lo][hi * 8];
        #pragma unroll
        for (int r = 0; r < 4; r++)
            #pragma unroll
            for (int c = 0; c < 4; c++)
                acc[r][c] = __builtin_amdgcn_mfma_f32_16x16x32_bf16(af[r], bfr[c], acc[r][c], 0, 0, 0);
        __syncthreads();
    }

    if (SPLITV) {
        int which = (n0 >> 7) % 3;
        if (which == 2) {
            int head = n0 / 384;
            #pragma unroll
            for (int c = 0; c < 4; c++) {
                int d = wc * 64 + c * 16 + lo;
                float bi = bias[n0 + d];
                #pragma unroll
                for (int r = 0; r < 4; r++) {
                    int gr = m0 + wr * 64 + r * 16 + hi * 4;
                    ushort4 o;
                    o.x = f2bf(acc[r][c][0] + bi);
                    o.y = f2bf(acc[r][c][1] + bi);
                    o.z = f2bf(acc[r][c][2] + bi);
                    o.w = f2bf(acc[r][c][3] + bi);
                    *(ushort4*)(vtb + ((size_t)(head * HD + d) * SQ + gr)) = o;
                }
            }
            return;
        }
    }

    #pragma unroll
    for (int c = 0; c < 4; c++) {
        int gc = n0 + wc * 64 + c * 16 + lo;
        float bi = bias[gc];
        #pragma unroll
        for (int r = 0; r < 4; r++) {
            #pragma unroll
            for (int i = 0; i < 4; i++) {
                int gr = m0 + wr * 64 + r * 16 + hi * 4 + i;
                float v = acc[r][c][i] + bi;
                if (GELU_ON) v = gelu_f(v);
                if (RES) v += res[(size_t)gr * N + gc];
                if (OUT_BF16) ((unsigned short*)outp)[(size_t)gr * N + gc] = f2bf(v);
                else          ((float*)outp)[(size_t)gr * N + gc] = v;
            }
        }
    }
}

// ---------------- Flash attention: 32x32 MFMA, causal + alibi ----------------
// 512 blocks (XCD-remapped: 2 heads/XCD), 128 threads = 2 waves x 32 q-rows.
// KVBLK=64. K,V^T staged via gld16 into linear LDS w/ XOR-swizzled source
// (chunk ^= row&7); ds_read_b128 with same XOR -> balanced banks.
// Swapped QK^T (A=K,B=Q): lane(l32,h2) holds P[q=l32][k-interleave], row
// reduce = 1 shfl_xor(32). P frags built in-register (select+2 shfl).
__global__ __launch_bounds__(128) void attn_kernel(
    const unsigned short* __restrict__ qkvB,  // [S][6144] bf16 (q,k valid; v garbage)
    const unsigned short* __restrict__ vtb,   // [NH][HD][S] bf16
    unsigned short* __restrict__ ctx)         // [S][2048] bf16
{
    int w = blockIdx.x;
    int lid = (w & 7) * 64 + (w >> 3);
    int n = lid >> 5, qt = lid & 31;
    int t = threadIdx.x, lane = t & 63, wid = t >> 6;
    int l32 = lane & 31, h2 = lane >> 5;
    int q0 = qt * 64, qg = q0 + wid * 32 + l32;

    __shared__ __align__(16) unsigned short Ks[64][128];
    __shared__ __align__(16) unsigned short Vt[128][64];

    bf16x8 qf[8];
    const unsigned short* qp = qkvB + (size_t)qg * QKVW + n * 384 + h2 * 8;
    #pragma unroll
    for (int d8 = 0; d8 < 8; d8++)
        qf[d8] = *(const bf16x8*)(qp + d8 * 16);

    const float slope = exp2f(-0.5f * (float)(n + 1));
    const float inv = 0.08838834764831845f;   // 1/sqrt(128)
    float m = -INFINITY, lsum = 0.f;
    f32x16 ao[4] = {};

    int krow = lane >> 4, kch = lane & 15;
    int vrow = lane >> 3, vch = lane & 7;
    const unsigned short* kb_ = qkvB + n * 384 + 128;
    const unsigned short* vb_ = vtb + (size_t)n * HD * SQ;
    const char* ksb = (const char*)&Ks[0][0];
    const char* vsb = (const char*)&Vt[0][0];

    int nkb = qt + 1;
    for (int kb = 0; kb < nkb; kb++) {
        int k0 = kb * 64;
        __syncthreads();
        #pragma unroll
        for (int s = 0; s < 8; s++) {
            int r = wid * 32 + s * 4 + krow;
            gld16(&Ks[wid * 32 + s * 4][0],
                  kb_ + (size_t)(k0 + r) * QKVW + ((kch ^ (r & 7)) << 3));
            int dd = wid * 64 + s * 8 + vrow;
            gld16(&Vt[wid * 64 + s * 8][0],
                  vb_ + (size_t)dd * SQ + k0 + ((vch ^ (dd & 7)) << 3));
        }
        __syncthreads();

        // ---- QK^T: sc0 = K[k0..k0+32) x Q, sc1 = K[k0+32..k0+64) x Q
        f32x16 sc0 = {}, sc1 = {};
        #pragma unroll
        for (int d8 = 0; d8 < 8; d8++) {
            int ch = ((d8 * 2 + h2) ^ (l32 & 7)) << 4;
            bf16x8 kf0 = *(const bf16x8*)(ksb + l32 * 256 + ch);
            bf16x8 kf1 = *(const bf16x8*)(ksb + (32 + l32) * 256 + ch);
            sc0 = __builtin_amdgcn_mfma_f32_32x32x16_bf16(kf0, qf[d8], sc0, 0, 0, 0);
            sc1 = __builtin_amdgcn_mfma_f32_32x32x16_bf16(kf1, qf[d8], sc1, 0, 0, 0);
        }

        // ---- softmax (scores in-place; lane holds q=l32, 32 k values)
        float tmax = -INFINITY;
        int last = (kb == nkb - 1);
        #pragma unroll
        for (int r = 0; r < 16; r++) {
            int kl = (r & 3) + 8 * (r >> 2) + 4 * h2;
            float s0 = sc0[r] * inv + slope * (float)(k0 + kl);
            float s1 = sc1[r] * inv + slope * (float)(k0 + 32 + kl);
            if (last) {
                if (k0 + kl > qg) s0 = -INFINITY;
                if (k0 + 32 + kl > qg) s1 = -INFINITY;
            }
            sc0[r] = s0; sc1[r] = s1;
            tmax = fmaxf(tmax, fmaxf(s0, s1));
        }
        tmax = fmaxf(tmax, __shfl_xor(tmax, 32));
        if (!__all(tmax <= m + 8.f)) {          // defer-max (T13)
            float mnew = fmaxf(m, tmax);
            float sca = __expf(m - mnew);
            m = mnew;
            lsum *= sca;
            #pragma unroll
            for (int db = 0; db < 4; db++)
                #pragma unroll
                for (int e = 0; e < 16; e++) ao[db][e] *= sca;
        }
        float psum = 0.f;
        #pragma unroll
        for (int r = 0; r < 16; r++) {
            sc0[r] = __expf(sc0[r] - m); psum += sc0[r];
            sc1[r] = __expf(sc1[r] - m); psum += sc1[r];
        }
        psum += __shfl_xor(psum, 32);
        lsum += psum;

        // ---- P fragments (in-register) + PV
        #pragma unroll
        for (int kstep = 0; kstep < 4; kstep++) {
            const int ks1 = kstep & 1;
            float a0, a1, a2, a3, b0, b1, b2, b3;
            if (kstep < 2) {
                a0 = sc0[8*ks1+0]; a1 = sc0[8*ks1+1]; a2 = sc0[8*ks1+2]; a3 = sc0[8*ks1+3];
                b0 = sc0[8*ks1+4]; b1 = sc0[8*ks1+5]; b2 = sc0[8*ks1+6]; b3 = sc0[8*ks1+7];
            } else {
                a0 = sc1[8*ks1+0]; a1 = sc1[8*ks1+1]; a2 = sc1[8*ks1+2]; a3 = sc1[8*ks1+3];
                b0 = sc1[8*ks1+4]; b1 = sc1[8*ks1+5]; b2 = sc1[8*ks1+6]; b3 = sc1[8*ks1+7];
            }
            unsigned ku0 = pack_bf2(h2 ? b0 : a0, h2 ? b1 : a1);
            unsigned ku1 = pack_bf2(h2 ? b2 : a2, h2 ? b3 : a3);
            unsigned su0 = pack_bf2(h2 ? a0 : b0, h2 ? a1 : b1);
            unsigned su1 = pack_bf2(h2 ? a2 : b2, h2 ? a3 : b3);
            unsigned r0 = (unsigned)__shfl_xor((int)su0, 32);
            unsigned r1 = (unsigned)__shfl_xor((int)su1, 32);
            union { int4 i; bf16x8 v; } u;
            u.i.x = h2 ? (int)r0  : (int)ku0;
            u.i.y = h2 ? (int)r1  : (int)ku1;
            u.i.z = h2 ? (int)ku0 : (int)r0;
            u.i.w = h2 ? (int)ku1 : (int)r1;
            bf16x8 pf = u.v;
            int ch = ((kstep * 2 + h2) ^ (l32 & 7)) << 4;
            #pragma unroll
            for (int db = 0; db < 4; db++) {
                bf16x8 vf = *(const bf16x8*)(vsb + (db * 32 + l32) * 128 + ch);
                ao[db] = __builtin_amdgcn_mfma_f32_32x32x16_bf16(vf, pf, ao[db], 0, 0, 0);
            }
        }
    }

    float rl = 1.f / lsum;
    #pragma unroll
    for (int db = 0; db < 4; db++)
        #pragma unroll
        for (int g = 0; g < 4; g++) {
            ushort4 o;
            o.x = f2bf(ao[db][g*4+0] * rl);
            o.y = f2bf(ao[db][g*4+1] * rl);
            o.z = f2bf(ao[db][g*4+2] * rl);
            o.w = f2bf(ao[db][g*4+3] * rl);
            *(ushort4*)(ctx + (size_t)qg * HH + n * HD + db * 32 + g * 8 + h2 * 4) = o;
        }
}

extern "C" void kernel_launch(void* const* d_in, const int* in_sizes, int n_in,
                              void* d_out, int out_size, void* d_ws, size_t ws_size,
                              hipStream_t stream) {
    const float* hs    = (const float*)d_in[0];
    const float* ln1g  = (const float*)d_in[4];
    const float* ln1b  = (const float*)d_in[5];
    const float* qkvw  = (const float*)d_in[6];
    const float* qkvb  = (const float*)d_in[7];
    const float* dw    = (const float*)d_in[8];
    const float* db    = (const float*)d_in[9];
    const float* ln2g  = (const float*)d_in[10];
    const float* ln2b  = (const float*)d_in[11];
    const float* f1w   = (const float*)d_in[12];
    const float* f1b   = (const float*)d_in[13];
    const float* f2w   = (const float*)d_in[14];
    const float* f2b   = (const float*)d_in[15];
    float* out = (float*)d_out;

    char* ws = (char*)d_ws;
    size_t off = 0;
    auto alloc = [&](size_t nbytes) {
        void* p = ws + off; off += (nbytes + 255) & ~(size_t)255; return p;
    };
    unsigned short* xbf  = (unsigned short*)alloc((size_t)SQ * HH * 2);
    unsigned short* qkvB = (unsigned short*)alloc((size_t)SQ * QKVW * 2);
    unsigned short* vtB  = (unsigned short*)alloc((size_t)NHEAD * HD * SQ * 2);
    unsigned short* ctx  = (unsigned short*)alloc((size_t)SQ * HH * 2);
    float*          attn = (float*)alloc((size_t)SQ * HH * 4);
    unsigned short* y    = (unsigned short*)alloc((size_t)SQ * HH * 2);
    unsigned short* hdn  = (unsigned short*)alloc((size_t)SQ * 4 * HH * 2);
    unsigned short* wbuf = (unsigned short*)alloc((size_t)4 * HH * HH * 2);

    ln_kernel<<<SQ, 256, 0, stream>>>(hs, ln1g, ln1b, xbf);

    cvt_kernel<<<2048, 256, 0, stream>>>(qkvw, wbuf, QKVW * HH / 4);
    gemm_bt<1, 0, 0, 1><<<dim3(QKVW / 128, SQ / 128), 256, 0, stream>>>(
        xbf, wbuf, qkvb, nullptr, qkvB, vtB, SQ, QKVW, HH);

    attn_kernel<<<512, 128, 0, stream>>>(qkvB, vtB, ctx);

    cvt_kernel<<<1024, 256, 0, stream>>>(dw, wbuf, HH * HH / 4);
    gemm_bt<0, 1, 0, 0><<<dim3(HH / 128, SQ / 128), 256, 0, stream>>>(
        ctx, wbuf, db, hs, attn, nullptr, SQ, HH, HH);

    ln_kernel<<<SQ, 256, 0, stream>>>(attn, ln2g, ln2b, y);

    cvt_kernel<<<2048, 256, 0, stream>>>(f1w, wbuf, 4 * HH * HH / 4);
    gemm_bt<1, 0, 1, 0><<<dim3(4 * HH / 128, SQ / 128), 256, 0, stream>>>(
        y, wbuf, f1b, nullptr, hdn, nullptr, SQ, 4 * HH, HH);

    cvt_kernel<<<2048, 256, 0, stream>>>(f2w, wbuf, 4 * HH * HH / 4);
    gemm_bt<0, 1, 0, 0><<<dim3(HH / 128, SQ / 128), 256, 0, stream>>>(
        hdn, wbuf, f2b, attn, out, nullptr, SQ, HH, 4 * HH);
}

// Round 4
// 572.242 us; speedup vs baseline: 1.4489x; 1.0371x over previous
//
#include <hip/hip_runtime.h>
#include <hip/hip_bf16.h>

#define SQ 2048
#define HH 2048
#define NHEAD 16
#define HD 128
#define QKVW (NHEAD*3*HD)   // 6144

typedef __attribute__((ext_vector_type(8))) short bf16x8;
typedef __attribute__((ext_vector_type(4))) float f32x4;
typedef __attribute__((ext_vector_type(16))) float f32x16;

__device__ inline unsigned short f2bf(float f) {
    union { float f; unsigned u; } x; x.f = f;
    unsigned r = x.u + 0x7FFFu + ((x.u >> 16) & 1u);
    return (unsigned short)(r >> 16);
}

__device__ inline unsigned pack_bf2(float a, float b) {
    return (unsigned)f2bf(a) | ((unsigned)f2bf(b) << 16);
}

__device__ inline float gelu_f(float x) {
    float x3 = x * (1.f + 0.044715f * x * x);
    return 0.5f * x * (1.f + tanhf(0.79788456f * x3));
}

// async global->LDS, 16B per lane. lds must be wave-uniform; g is per-lane.
__device__ inline void gld16(void* lds, const void* g) {
    __builtin_amdgcn_global_load_lds(
        (__attribute__((address_space(1))) void*)(g),
        (__attribute__((address_space(3))) void*)(lds), 16, 0, 0);
}

// ---------------- fp32 -> bf16 convert ----------------
__global__ __launch_bounds__(256) void cvt_kernel(
    const float* __restrict__ in, unsigned short* __restrict__ out, int n4)
{
    int i = blockIdx.x * blockDim.x + threadIdx.x;
    int stride = gridDim.x * blockDim.x;
    for (; i < n4; i += stride) {
        float4 f = ((const float4*)in)[i];
        ushort4 o;
        o.x = f2bf(f.x); o.y = f2bf(f.y); o.z = f2bf(f.z); o.w = f2bf(f.w);
        ((ushort4*)out)[i] = o;
    }
}

// ---------------- LayerNorm: fp32 in -> bf16 out ----------------
__global__ __launch_bounds__(256) void ln_kernel(
    const float* __restrict__ in, const float* __restrict__ g,
    const float* __restrict__ b, unsigned short* __restrict__ out)
{
    int row = blockIdx.x;
    int t = threadIdx.x, lane = t & 63, wid = t >> 6;
    const float4* rp = (const float4*)(in + (size_t)row * HH);
    float4 v0 = rp[t], v1 = rp[t + 256];
    float s  = v0.x + v0.y + v0.z + v0.w + v1.x + v1.y + v1.z + v1.w;
    float ss = v0.x*v0.x + v0.y*v0.y + v0.z*v0.z + v0.w*v0.w
             + v1.x*v1.x + v1.y*v1.y + v1.z*v1.z + v1.w*v1.w;
    #pragma unroll
    for (int o = 32; o; o >>= 1) { s += __shfl_down(s, o); ss += __shfl_down(ss, o); }
    __shared__ float r0[4], r1[4];
    if (lane == 0) { r0[wid] = s; r1[wid] = ss; }
    __syncthreads();
    s  = r0[0] + r0[1] + r0[2] + r0[3];
    ss = r1[0] + r1[1] + r1[2] + r1[3];
    float mu = s * (1.f / HH);
    float var = ss * (1.f / HH) - mu * mu;
    float rs = rsqrtf(var + 1e-5f);
    float4 g0 = ((const float4*)g)[t], g1 = ((const float4*)g)[t + 256];
    float4 b0 = ((const float4*)b)[t], b1 = ((const float4*)b)[t + 256];
    ushort4 o0, o1;
    o0.x = f2bf((v0.x - mu) * rs * g0.x + b0.x);
    o0.y = f2bf((v0.y - mu) * rs * g0.y + b0.y);
    o0.z = f2bf((v0.z - mu) * rs * g0.z + b0.z);
    o0.w = f2bf((v0.w - mu) * rs * g0.w + b0.w);
    o1.x = f2bf((v1.x - mu) * rs * g1.x + b1.x);
    o1.y = f2bf((v1.y - mu) * rs * g1.y + b1.y);
    o1.z = f2bf((v1.z - mu) * rs * g1.z + b1.z);
    o1.w = f2bf((v1.w - mu) * rs * g1.w + b1.w);
    ushort4* op = (ushort4*)(out + (size_t)row * HH);
    op[t] = o0; op[t + 256] = o1;
}

// ---------------- reduce: out = p0 + p1 + res + bias ----------------
__global__ __launch_bounds__(256) void reduce2_kernel(
    const float* __restrict__ p, const float* __restrict__ res,
    const float* __restrict__ bias, float* __restrict__ out, int n4, int nc4m1)
{
    int i = blockIdx.x * blockDim.x + threadIdx.x;
    int st = gridDim.x * blockDim.x;
    const float4* p0 = (const float4*)p;
    const float4* p1 = p0 + n4;
    for (; i < n4; i += st) {
        float4 a = p0[i], b = p1[i];
        float4 r = ((const float4*)res)[i];
        float4 bv = ((const float4*)bias)[i & nc4m1];
        float4 o;
        o.x = a.x + b.x + r.x + bv.x;
        o.y = a.y + b.y + r.y + bv.y;
        o.z = a.z + b.z + r.z + bv.z;
        o.w = a.w + b.w + r.w + bv.w;
        ((float4*)out)[i] = o;
    }
}

// =============== 256x256 8-phase GEMM (T1+T2+T3+T4+T5) ===============
// C[M,N] = A[M,K]bf16 @ B[N,K]bf16^T. BK=64, 512 thr = 8 waves (2Mx4N),
// per-wave C 128x64 (8x4 16x16 frags). LDS 2buf x (A 256x64 + B 256x64).
// Stage regions (each = 2 gld16/thread): Aa=A-rows{0-63,128-191},
// Ab={64-127,192-255}, Bg=B-rows ==0..31 mod 64, Bd= ==32..63 mod 64.
// Phase p of tile u reads quadrant (qr,qc); region deaths: Aa@ph2, Bg@ph3,
// Ab,Bd@ph4. Stage schedule (into dead regions only):
//   ph1: Ab(u+1)->buf^1   ph2: Bd(u+1)->buf^1
//   ph3: Aa(u+2)->buf     ph4: Bg(u+2)->buf, then vmcnt(4)
// LDS chunk-swizzle: LDS[r][c] holds global chunk c^(r&7) (16B chunks).

__device__ __forceinline__ void stageA(unsigned short (*dst)[64],
    const unsigned short* Abase, int ld, int h, int wid, int lane)
{
    int rb = (wid >> 2) * 128 + h * 64 + (wid & 3) * 16;
    #pragma unroll
    for (int j = 0; j < 2; j++) {
        int r = rb + j * 8 + (lane >> 3);
        int ch = (lane & 7) ^ (r & 7);
        gld16(&dst[rb + j * 8][0], Abase + (size_t)r * ld + ch * 8);
    }
}

__device__ __forceinline__ void stageB(unsigned short (*dst)[64],
    const unsigned short* Bbase, int ld, int h, int wid, int lane)
{
    int rb = (wid >> 1) * 64 + h * 32 + (wid & 1) * 16;
    #pragma unroll
    for (int j = 0; j < 2; j++) {
        int r = rb + j * 8 + (lane >> 3);
        int ch = (lane & 7) ^ (r & 7);
        gld16(&dst[rb + j * 8][0], Bbase + (size_t)r * ld + ch * 8);
    }
}

template<int QR, int QC>
__device__ __forceinline__ void phase_loads(
    const unsigned short (*ldsA)[64], const unsigned short (*ldsB)[64],
    bf16x8 (&af)[2][4], bf16x8 (&bfr)[2][2], int wr, int wc, int lo, int hi)
{
    #pragma unroll
    for (int ks = 0; ks < 2; ks++) {
        int g = ks * 4 + hi;
        #pragma unroll
        for (int i = 0; i < 4; i++) {
            int r = wr * 128 + QR * 64 + i * 16 + lo;
            af[ks][i] = *(const bf16x8*)&ldsA[r][(g ^ (r & 7)) << 3];
        }
        #pragma unroll
        for (int c = 0; c < 2; c++) {
            int r = wc * 64 + QC * 32 + c * 16 + lo;
            bfr[ks][c] = *(const bf16x8*)&ldsB[r][(g ^ (r & 7)) << 3];
        }
    }
}

template<int QR, int QC>
__device__ __forceinline__ void phase_mfma(
    const bf16x8 (&af)[2][4], const bf16x8 (&bfr)[2][2], f32x4 (&acc)[8][4])
{
    __builtin_amdgcn_s_barrier();
    asm volatile("s_waitcnt lgkmcnt(0)" ::: "memory");
    __builtin_amdgcn_sched_barrier(0);
    __builtin_amdgcn_s_setprio(1);
    #pragma unroll
    for (int ks = 0; ks < 2; ks++)
        #pragma unroll
        for (int i = 0; i < 4; i++)
            #pragma unroll
            for (int c = 0; c < 2; c++)
                acc[QR*4+i][QC*2+c] = __builtin_amdgcn_mfma_f32_16x16x32_bf16(
                    af[ks][i], bfr[ks][c], acc[QR*4+i][QC*2+c], 0, 0, 0);
    __builtin_amdgcn_s_setprio(0);
    __builtin_amdgcn_s_barrier();
}

// MODE: 0 = fp32 partial (no bias), 1 = bf16 + bias (+GELU), 2 = QKV splitV
template<int MODE, int GELU_ON>
__global__ __launch_bounds__(512, 2) void gemm256(
    const unsigned short* __restrict__ A, const unsigned short* __restrict__ B,
    const float* __restrict__ bias, void* __restrict__ outp,
    unsigned short* __restrict__ vtb, int N, int lda, int ldb, int kLen)
{
    __shared__ unsigned short lds[2][2][256][64];   // 128 KiB

    int t = threadIdx.x, lane = t & 63, wid = t >> 6;
    int lo = lane & 15, hi = lane >> 4;
    int wr = wid >> 2, wc = wid & 3;

    // XCD-aware bijective swizzle (nwg % 8 == 0 for all our launches)
    int gx = gridDim.x;
    int nwg = gx * gridDim.y;
    int id = blockIdx.y * gx + blockIdx.x;
    int swz = (id & 7) * (nwg >> 3) + (id >> 3);
    int bm = swz / gx, bn = swz % gx;
    int m0 = bm * 256, n0 = bn * 256;
    int kstart = blockIdx.z * kLen;

    const unsigned short* At = A + (size_t)m0 * lda + kstart;
    const unsigned short* Bt = B + (size_t)n0 * ldb + kstart;
    int nt = kLen >> 6;

    // prologue: tile0 full + Aa(1), Bg(1); then vmcnt(4)
    stageA(lds[0][0], At, lda, 0, wid, lane);
    stageB(lds[0][1], Bt, ldb, 0, wid, lane);
    stageA(lds[0][0], At, lda, 1, wid, lane);
    stageB(lds[0][1], Bt, ldb, 1, wid, lane);
    int k1 = (nt > 1) ? 64 : 0;
    stageA(lds[1][0], At + k1, lda, 0, wid, lane);
    stageB(lds[1][1], Bt + k1, ldb, 0, wid, lane);
    asm volatile("s_waitcnt vmcnt(4)" ::: "memory");
    __builtin_amdgcn_s_barrier();

    f32x4 acc[8][4] = {};
    for (int u = 0; u < nt; u++) {
        int buf = u & 1;
        int t1 = (u + 1 < nt) ? u + 1 : nt - 1;
        int t2 = (u + 2 < nt) ? u + 2 : nt - 1;
        {   bf16x8 af[2][4], bfr[2][2];
            phase_loads<0,0>(lds[buf][0], lds[buf][1], af, bfr, wr, wc, lo, hi);
            stageA(lds[buf^1][0], At + t1 * 64, lda, 1, wid, lane);
            phase_mfma<0,0>(af, bfr, acc);
        }
        {   bf16x8 af[2][4], bfr[2][2];
            phase_loads<0,1>(lds[buf][0], lds[buf][1], af, bfr, wr, wc, lo, hi);
            stageB(lds[buf^1][1], Bt + t1 * 64, ldb, 1, wid, lane);
            phase_mfma<0,1>(af, bfr, acc);
        }
        {   bf16x8 af[2][4], bfr[2][2];
            phase_loads<1,0>(lds[buf][0], lds[buf][1], af, bfr, wr, wc, lo, hi);
            stageA(lds[buf][0], At + t2 * 64, lda, 0, wid, lane);
            phase_mfma<1,0>(af, bfr, acc);
        }
        {   bf16x8 af[2][4], bfr[2][2];
            phase_loads<1,1>(lds[buf][0], lds[buf][1], af, bfr, wr, wc, lo, hi);
            stageB(lds[buf][1], Bt + t2 * 64, ldb, 0, wid, lane);
            asm volatile("s_waitcnt vmcnt(4)" ::: "memory");
            phase_mfma<1,1>(af, bfr, acc);
        }
    }

    // ---- epilogue ----
    if (MODE == 0) {
        float* po = (float*)outp + (size_t)blockIdx.z * SQ * N;
        #pragma unroll
        for (int ci = 0; ci < 4; ci++) {
            int gc = n0 + wc * 64 + ci * 16 + lo;
            #pragma unroll
            for (int ri = 0; ri < 8; ri++)
                #pragma unroll
                for (int ii = 0; ii < 4; ii++) {
                    int gr = m0 + wr * 128 + ri * 16 + hi * 4 + ii;
                    po[(size_t)gr * N + gc] = acc[ri][ci][ii];
                }
        }
    } else if (MODE == 1) {
        unsigned short* op = (unsigned short*)outp;
        #pragma unroll
        for (int ci = 0; ci < 4; ci++) {
            int gc = n0 + wc * 64 + ci * 16 + lo;
            float bi = bias[gc];
            #pragma unroll
            for (int ri = 0; ri < 8; ri++)
                #pragma unroll
                for (int ii = 0; ii < 4; ii++) {
                    int gr = m0 + wr * 128 + ri * 16 + hi * 4 + ii;
                    float v = acc[ri][ci][ii] + bi;
                    if (GELU_ON) v = gelu_f(v);
                    op[(size_t)gr * N + gc] = f2bf(v);
                }
        }
    } else {
        unsigned short* op = (unsigned short*)outp;
        #pragma unroll
        for (int ci = 0; ci < 4; ci++) {
            int gc = n0 + wc * 64 + ci * 16 + lo;
            int head = gc / 384;
            int within = gc - head * 384;
            float bi = bias[gc];
            if (within >= 256) {            // V column -> transposed store
                int d = within - 256;
                #pragma unroll
                for (int ri = 0; ri < 8; ri++) {
                    int gr = m0 + wr * 128 + ri * 16 + hi * 4;
                    ushort4 o;
                    o.x = f2bf(acc[ri][ci][0] + bi);
                    o.y = f2bf(acc[ri][ci][1] + bi);
                    o.z = f2bf(acc[ri][ci][2] + bi);
                    o.w = f2bf(acc[ri][ci][3] + bi);
                    *(ushort4*)(vtb + ((size_t)(head * HD + d) * SQ + gr)) = o;
                }
            } else {
                #pragma unroll
                for (int ri = 0; ri < 8; ri++)
                    #pragma unroll
                    for (int ii = 0; ii < 4; ii++) {
                        int gr = m0 + wr * 128 + ri * 16 + hi * 4 + ii;
                        op[(size_t)gr * N + gc] = f2bf(acc[ri][ci][ii] + bi);
                    }
            }
        }
    }
}

// ---------------- Flash attention: 32x32 MFMA, causal + alibi ----------------
__global__ __launch_bounds__(128) void attn_kernel(
    const unsigned short* __restrict__ qkvB,  // [S][6144] bf16 (q,k valid)
    const unsigned short* __restrict__ vtb,   // [NH][HD][S] bf16
    unsigned short* __restrict__ ctx)         // [S][2048] bf16
{
    int w = blockIdx.x;
    int lid = (w & 7) * 64 + (w >> 3);
    int n = lid >> 5, qt = lid & 31;
    int t = threadIdx.x, lane = t & 63, wid = t >> 6;
    int l32 = lane & 31, h2 = lane >> 5;
    int q0 = qt * 64, qg = q0 + wid * 32 + l32;

    __shared__ __align__(16) unsigned short Ks[64][128];
    __shared__ __align__(16) unsigned short Vt[128][64];

    bf16x8 qf[8];
    const unsigned short* qp = qkvB + (size_t)qg * QKVW + n * 384 + h2 * 8;
    #pragma unroll
    for (int d8 = 0; d8 < 8; d8++)
        qf[d8] = *(const bf16x8*)(qp + d8 * 16);

    const float slope = exp2f(-0.5f * (float)(n + 1));
    const float inv = 0.08838834764831845f;   // 1/sqrt(128)
    float m = -INFINITY, lsum = 0.f;
    f32x16 ao[4] = {};

    int krow = lane >> 4, kch = lane & 15;
    int vrow = lane >> 3, vch = lane & 7;
    const unsigned short* kb_ = qkvB + n * 384 + 128;
    const unsigned short* vb_ = vtb + (size_t)n * HD * SQ;
    const char* ksb = (const char*)&Ks[0][0];
    const char* vsb = (const char*)&Vt[0][0];

    int nkb = qt + 1;
    for (int kb = 0; kb < nkb; kb++) {
        int k0 = kb * 64;
        __syncthreads();
        #pragma unroll
        for (int s = 0; s < 8; s++) {
            int r = wid * 32 + s * 4 + krow;
            gld16(&Ks[wid * 32 + s * 4][0],
                  kb_ + (size_t)(k0 + r) * QKVW + ((kch ^ (r & 7)) << 3));
            int dd = wid * 64 + s * 8 + vrow;
            gld16(&Vt[wid * 64 + s * 8][0],
                  vb_ + (size_t)dd * SQ + k0 + ((vch ^ (dd & 7)) << 3));
        }
        __syncthreads();

        f32x16 sc0 = {}, sc1 = {};
        #pragma unroll
        for (int d8 = 0; d8 < 8; d8++) {
            int ch = ((d8 * 2 + h2) ^ (l32 & 7)) << 4;
            bf16x8 kf0 = *(const bf16x8*)(ksb + l32 * 256 + ch);
            bf16x8 kf1 = *(const bf16x8*)(ksb + (32 + l32) * 256 + ch);
            sc0 = __builtin_amdgcn_mfma_f32_32x32x16_bf16(kf0, qf[d8], sc0, 0, 0, 0);
            sc1 = __builtin_amdgcn_mfma_f32_32x32x16_bf16(kf1, qf[d8], sc1, 0, 0, 0);
        }

        float tmax = -INFINITY;
        int last = (kb == nkb - 1);
        #pragma unroll
        for (int r = 0; r < 16; r++) {
            int kl = (r & 3) + 8 * (r >> 2) + 4 * h2;
            float s0 = sc0[r] * inv + slope * (float)(k0 + kl);
            float s1 = sc1[r] * inv + slope * (float)(k0 + 32 + kl);
            if (last) {
                if (k0 + kl > qg) s0 = -INFINITY;
                if (k0 + 32 + kl > qg) s1 = -INFINITY;
            }
            sc0[r] = s0; sc1[r] = s1;
            tmax = fmaxf(tmax, fmaxf(s0, s1));
        }
        tmax = fmaxf(tmax, __shfl_xor(tmax, 32));
        if (!__all(tmax <= m + 8.f)) {          // defer-max (T13)
            float mnew = fmaxf(m, tmax);
            float sca = __expf(m - mnew);
            m = mnew;
            lsum *= sca;
            #pragma unroll
            for (int db = 0; db < 4; db++)
                #pragma unroll
                for (int e = 0; e < 16; e++) ao[db][e] *= sca;
        }
        float psum = 0.f;
        #pragma unroll
        for (int r = 0; r < 16; r++) {
            sc0[r] = __expf(sc0[r] - m); psum += sc0[r];
            sc1[r] = __expf(sc1[r] - m); psum += sc1[r];
        }
        psum += __shfl_xor(psum, 32);
        lsum += psum;

        #pragma unroll
        for (int kstep = 0; kstep < 4; kstep++) {
            const int ks1 = kstep & 1;
            float a0, a1, a2, a3, b0, b1, b2, b3;
            if (kstep < 2) {
                a0 = sc0[8*ks1+0]; a1 = sc0[8*ks1+1]; a2 = sc0[8*ks1+2]; a3 = sc0[8*ks1+3];
                b0 = sc0[8*ks1+4]; b1 = sc0[8*ks1+5]; b2 = sc0[8*ks1+6]; b3 = sc0[8*ks1+7];
            } else {
                a0 = sc1[8*ks1+0]; a1 = sc1[8*ks1+1]; a2 = sc1[8*ks1+2]; a3 = sc1[8*ks1+3];
                b0 = sc1[8*ks1+4]; b1 = sc1[8*ks1+5]; b2 = sc1[8*ks1+6]; b3 = sc1[8*ks1+7];
            }
            unsigned ku0 = pack_bf2(h2 ? b0 : a0, h2 ? b1 : a1);
            unsigned ku1 = pack_bf2(h2 ? b2 : a2, h2 ? b3 : a3);
            unsigned su0 = pack_bf2(h2 ? a0 : b0, h2 ? a1 : b1);
            unsigned su1 = pack_bf2(h2 ? a2 : b2, h2 ? a3 : b3);
            unsigned r0 = (unsigned)__shfl_xor((int)su0, 32);
            unsigned r1 = (unsigned)__shfl_xor((int)su1, 32);
            union { int4 i; bf16x8 v; } u;
            u.i.x = h2 ? (int)r0  : (int)ku0;
            u.i.y = h2 ? (int)r1  : (int)ku1;
            u.i.z = h2 ? (int)ku0 : (int)r0;
            u.i.w = h2 ? (int)ku1 : (int)r1;
            bf16x8 pf = u.v;
            int ch = ((kstep * 2 + h2) ^ (l32 & 7)) << 4;
            #pragma unroll
            for (int db = 0; db < 4; db++) {
                bf16x8 vf = *(const bf16x8*)(vsb + (db * 32 + l32) * 128 + ch);
                ao[db] = __builtin_amdgcn_mfma_f32_32x32x16_bf16(vf, pf, ao[db], 0, 0, 0);
            }
        }
    }

    float rl = 1.f / lsum;
    #pragma unroll
    for (int db = 0; db < 4; db++)
        #pragma unroll
        for (int g = 0; g < 4; g++) {
            ushort4 o;
            o.x = f2bf(ao[db][g*4+0] * rl);
            o.y = f2bf(ao[db][g*4+1] * rl);
            o.z = f2bf(ao[db][g*4+2] * rl);
            o.w = f2bf(ao[db][g*4+3] * rl);
            *(ushort4*)(ctx + (size_t)qg * HH + n * HD + db * 32 + g * 8 + h2 * 4) = o;
        }
}

extern "C" void kernel_launch(void* const* d_in, const int* in_sizes, int n_in,
                              void* d_out, int out_size, void* d_ws, size_t ws_size,
                              hipStream_t stream) {
    const float* hs    = (const float*)d_in[0];
    const float* ln1g  = (const float*)d_in[4];
    const float* ln1b  = (const float*)d_in[5];
    const float* qkvw  = (const float*)d_in[6];
    const float* qkvb  = (const float*)d_in[7];
    const float* dw    = (const float*)d_in[8];
    const float* db    = (const float*)d_in[9];
    const float* ln2g  = (const float*)d_in[10];
    const float* ln2b  = (const float*)d_in[11];
    const float* f1w   = (const float*)d_in[12];
    const float* f1b   = (const float*)d_in[13];
    const float* f2w   = (const float*)d_in[14];
    const float* f2b   = (const float*)d_in[15];
    float* out = (float*)d_out;

    char* ws = (char*)d_ws;
    size_t off = 0;
    auto alloc = [&](size_t nbytes) {
        void* p = ws + off; off += (nbytes + 255) & ~(size_t)255; return p;
    };
    unsigned short* xbf  = (unsigned short*)alloc((size_t)SQ * HH * 2);        // 8.4 MB
    unsigned short* qkvB = (unsigned short*)alloc((size_t)SQ * QKVW * 2);      // 25.2 MB
    unsigned short* vtB  = (unsigned short*)alloc((size_t)NHEAD * HD * SQ * 2);// 8.4 MB
    unsigned short* ctx  = (unsigned short*)alloc((size_t)SQ * HH * 2);        // 8.4 MB
    float*          attn = (float*)alloc((size_t)SQ * HH * 4);                 // 16.8 MB
    unsigned short* y    = (unsigned short*)alloc((size_t)SQ * HH * 2);
    unsigned short* hdn  = (unsigned short*)alloc((size_t)SQ * 4 * HH * 2);
    unsigned short* wbuf = (unsigned short*)alloc((size_t)4 * HH * HH * 2);
    // split-K partials (2 x 16.8 MB fp32) overlap dead xbf+qkvB exactly
    float* part = (float*)ws;

    ln_kernel<<<SQ, 256, 0, stream>>>(hs, ln1g, ln1b, xbf);

    cvt_kernel<<<2048, 256, 0, stream>>>(qkvw, wbuf, QKVW * HH / 4);
    gemm256<2, 0><<<dim3(QKVW / 256, SQ / 256, 1), 512, 0, stream>>>(
        xbf, wbuf, qkvb, qkvB, vtB, QKVW, HH, HH, HH);

    attn_kernel<<<512, 128, 0, stream>>>(qkvB, vtB, ctx);

    cvt_kernel<<<1024, 256, 0, stream>>>(dw, wbuf, HH * HH / 4);
    gemm256<0, 0><<<dim3(HH / 256, SQ / 256, 2), 512, 0, stream>>>(
        ctx, wbuf, nullptr, part, nullptr, HH, HH, HH, HH / 2);
    reduce2_kernel<<<2048, 256, 0, stream>>>(part, hs, db, attn, SQ * HH / 4, HH / 4 - 1);

    ln_kernel<<<SQ, 256, 0, stream>>>(attn, ln2g, ln2b, y);

    cvt_kernel<<<2048, 256, 0, stream>>>(f1w, wbuf, 4 * HH * HH / 4);
    gemm256<1, 1><<<dim3(4 * HH / 256, SQ / 256, 1), 512, 0, stream>>>(
        y, wbuf, f1b, hdn, nullptr, 4 * HH, HH, HH, HH);

    cvt_kernel<<<2048, 256, 0, stream>>>(f2w, wbuf, 4 * HH * HH / 4);
    gemm256<0, 0><<<dim3(HH / 256, SQ / 256, 2), 512, 0, stream>>>(
        hdn, wbuf, nullptr, part, nullptr, HH, 4 * HH, 4 * HH, 2 * HH);
    reduce2_kernel<<<2048, 256, 0, stream>>>(part, attn, f2b, out, SQ * HH / 4, HH / 4 - 1);
}

// Round 5
// 492.212 us; speedup vs baseline: 1.6845x; 1.1626x over previous
//
#include <hip/hip_runtime.h>
#include <hip/hip_bf16.h>

#define SQ 2048
#define HH 2048
#define NHEAD 16
#define HD 128
#define QKVW (NHEAD*3*HD)   // 6144

typedef __attribute__((ext_vector_type(8))) short bf16x8;
typedef __attribute__((ext_vector_type(4))) float f32x4;
typedef __attribute__((ext_vector_type(16))) float f32x16;

__device__ inline unsigned short f2bf(float f) {
    union { float f; unsigned u; } x; x.f = f;
    unsigned r = x.u + 0x7FFFu + ((x.u >> 16) & 1u);
    return (unsigned short)(r >> 16);
}

__device__ inline unsigned pack_bf2(float a, float b) {
    return (unsigned)f2bf(a) | ((unsigned)f2bf(b) << 16);
}

__device__ inline float gelu_f(float x) {
    float x3 = x * (1.f + 0.044715f * x * x);
    return 0.5f * x * (1.f + tanhf(0.79788456f * x3));
}

// async global->LDS, 16B per lane. lds must be wave-uniform; g is per-lane.
__device__ inline void gld16(void* lds, const void* g) {
    __builtin_amdgcn_global_load_lds(
        (__attribute__((address_space(1))) void*)(g),
        (__attribute__((address_space(3))) void*)(lds), 16, 0, 0);
}

// ---------------- fp32 -> bf16 convert ----------------
__global__ __launch_bounds__(256) void cvt_kernel(
    const float* __restrict__ in, unsigned short* __restrict__ out, int n4)
{
    int i = blockIdx.x * blockDim.x + threadIdx.x;
    int stride = gridDim.x * blockDim.x;
    for (; i < n4; i += stride) {
        float4 f = ((const float4*)in)[i];
        ushort4 o;
        o.x = f2bf(f.x); o.y = f2bf(f.y); o.z = f2bf(f.z); o.w = f2bf(f.w);
        ((ushort4*)out)[i] = o;
    }
}

// ---------------- LayerNorm: fp32 in -> bf16 out ----------------
__global__ __launch_bounds__(256) void ln_kernel(
    const float* __restrict__ in, const float* __restrict__ g,
    const float* __restrict__ b, unsigned short* __restrict__ out)
{
    int row = blockIdx.x;
    int t = threadIdx.x, lane = t & 63, wid = t >> 6;
    const float4* rp = (const float4*)(in + (size_t)row * HH);
    float4 v0 = rp[t], v1 = rp[t + 256];
    float s  = v0.x + v0.y + v0.z + v0.w + v1.x + v1.y + v1.z + v1.w;
    float ss = v0.x*v0.x + v0.y*v0.y + v0.z*v0.z + v0.w*v0.w
             + v1.x*v1.x + v1.y*v1.y + v1.z*v1.z + v1.w*v1.w;
    #pragma unroll
    for (int o = 32; o; o >>= 1) { s += __shfl_down(s, o); ss += __shfl_down(ss, o); }
    __shared__ float r0[4], r1[4];
    if (lane == 0) { r0[wid] = s; r1[wid] = ss; }
    __syncthreads();
    s  = r0[0] + r0[1] + r0[2] + r0[3];
    ss = r1[0] + r1[1] + r1[2] + r1[3];
    float mu = s * (1.f / HH);
    float var = ss * (1.f / HH) - mu * mu;
    float rs = rsqrtf(var + 1e-5f);
    float4 g0 = ((const float4*)g)[t], g1 = ((const float4*)g)[t + 256];
    float4 b0 = ((const float4*)b)[t], b1 = ((const float4*)b)[t + 256];
    ushort4 o0, o1;
    o0.x = f2bf((v0.x - mu) * rs * g0.x + b0.x);
    o0.y = f2bf((v0.y - mu) * rs * g0.y + b0.y);
    o0.z = f2bf((v0.z - mu) * rs * g0.z + b0.z);
    o0.w = f2bf((v0.w - mu) * rs * g0.w + b0.w);
    o1.x = f2bf((v1.x - mu) * rs * g1.x + b1.x);
    o1.y = f2bf((v1.y - mu) * rs * g1.y + b1.y);
    o1.z = f2bf((v1.z - mu) * rs * g1.z + b1.z);
    o1.w = f2bf((v1.w - mu) * rs * g1.w + b1.w);
    ushort4* op = (ushort4*)(out + (size_t)row * HH);
    op[t] = o0; op[t + 256] = o1;
}

// ---------------- reduce: out = sum(partials) + res + bias ----------------
template<int NP>
__global__ __launch_bounds__(256) void reduceN_kernel(
    const float* __restrict__ p0, const float* __restrict__ p1,
    const float* __restrict__ p2, const float* __restrict__ p3,
    const float* __restrict__ res, const float* __restrict__ bias,
    float* __restrict__ out, int n4, int nc4m1)
{
    int i = blockIdx.x * blockDim.x + threadIdx.x;
    int st = gridDim.x * blockDim.x;
    for (; i < n4; i += st) {
        float4 a = ((const float4*)p0)[i];
        float4 b = ((const float4*)p1)[i];
        float4 r = ((const float4*)res)[i];
        float4 bv = ((const float4*)bias)[i & nc4m1];
        float4 o;
        o.x = a.x + b.x + r.x + bv.x;
        o.y = a.y + b.y + r.y + bv.y;
        o.z = a.z + b.z + r.z + bv.z;
        o.w = a.w + b.w + r.w + bv.w;
        if (NP >= 3) {
            float4 c = ((const float4*)p2)[i];
            o.x += c.x; o.y += c.y; o.z += c.z; o.w += c.w;
        }
        if (NP >= 4) {
            float4 d = ((const float4*)p3)[i];
            o.x += d.x; o.y += d.y; o.z += d.z; o.w += d.w;
        }
        ((float4*)out)[i] = o;
    }
}

// =============== 256x256 3-phase GEMM (T1..T5, frag-reuse) ===============
// C[M,N] = A[M,K]bf16 @ B[N,K]bf16^T. BK=64, 512 thr = 8 waves (2Mx4N),
// per-wave C 128x64. LDS 2buf x (A 256x64 + B 256x64), chunk-XOR swizzle.
// Per tile: ph1 {read A-top+B-left -> Q00}, ph2 {read B-right -> Q01},
// ph3 {read A-bot -> Q11; Q10 reg-only; counted vmcnt(4)}. 24 b128/wave/tile.
// MFMA operand-swapped: acc = mfma(b,a) -> lane cols = M, regs = N (vec stores).

__device__ __forceinline__ void stageA(unsigned short (*dst)[64],
    const unsigned short* Abase, int ld, int h, int wid, int lane)
{
    int rb = (wid >> 2) * 128 + h * 64 + (wid & 3) * 16;
    #pragma unroll
    for (int j = 0; j < 2; j++) {
        int r = rb + j * 8 + (lane >> 3);
        int ch = (lane & 7) ^ (r & 7);
        gld16(&dst[rb + j * 8][0], Abase + (size_t)r * ld + ch * 8);
    }
}

__device__ __forceinline__ void stageB(unsigned short (*dst)[64],
    const unsigned short* Bbase, int ld, int h, int wid, int lane)
{
    int rb = (wid >> 1) * 64 + h * 32 + (wid & 1) * 16;
    #pragma unroll
    for (int j = 0; j < 2; j++) {
        int r = rb + j * 8 + (lane >> 3);
        int ch = (lane & 7) ^ (r & 7);
        gld16(&dst[rb + j * 8][0], Bbase + (size_t)r * ld + ch * 8);
    }
}

__device__ __forceinline__ void loadA(const unsigned short (*ldsA)[64],
    bf16x8 (&af)[2][4], int half, int wr, int lo, int hi)
{
    #pragma unroll
    for (int ks = 0; ks < 2; ks++) {
        int g = ks * 4 + hi;
        #pragma unroll
        for (int i = 0; i < 4; i++) {
            int r = wr * 128 + half * 64 + i * 16 + lo;
            af[ks][i] = *(const bf16x8*)&ldsA[r][(g ^ (r & 7)) << 3];
        }
    }
}

__device__ __forceinline__ void loadB(const unsigned short (*ldsB)[64],
    bf16x8 (&bf)[2][2], int half, int wc, int lo, int hi)
{
    #pragma unroll
    for (int ks = 0; ks < 2; ks++) {
        int g = ks * 4 + hi;
        #pragma unroll
        for (int c = 0; c < 2; c++) {
            int r = wc * 64 + half * 32 + c * 16 + lo;
            bf[ks][c] = *(const bf16x8*)&ldsB[r][(g ^ (r & 7)) << 3];
        }
    }
}

template<int QR, int QC>
__device__ __forceinline__ void mfma16(
    const bf16x8 (&bf)[2][2], const bf16x8 (&af)[2][4], f32x4 (&acc)[8][4])
{
    #pragma unroll
    for (int ks = 0; ks < 2; ks++)
        #pragma unroll
        for (int i = 0; i < 4; i++)
            #pragma unroll
            for (int c = 0; c < 2; c++)
                acc[QR*4+i][QC*2+c] = __builtin_amdgcn_mfma_f32_16x16x32_bf16(
                    bf[ks][c], af[ks][i], acc[QR*4+i][QC*2+c], 0, 0, 0);
}

#define PH_SYNC() do { \
    __builtin_amdgcn_s_barrier(); \
    asm volatile("s_waitcnt lgkmcnt(0)" ::: "memory"); \
    __builtin_amdgcn_sched_barrier(0); \
} while (0)

// MODE: 0 = fp32 partial (no bias), 1 = bf16 + bias (+GELU), 2 = QKV splitV
template<int MODE, int GELU_ON>
__global__ __launch_bounds__(512, 2) void gemm256(
    const unsigned short* __restrict__ A, const unsigned short* __restrict__ B,
    const float* __restrict__ bias, void* __restrict__ outp,
    unsigned short* __restrict__ vtb, void* __restrict__ outp_hi,
    int N, int lda, int ldb, int kLen, int Ktot)
{
    __shared__ unsigned short lds[2][2][256][64];   // 128 KiB

    int t = threadIdx.x, lane = t & 63, wid = t >> 6;
    int lo = lane & 15, hi = lane >> 4;
    int wr = wid >> 2, wc = wid & 3;

    // XCD-aware bijective swizzle (nwg % 8 == 0 for all our launches)
    int gx = gridDim.x;
    int nwg = gx * gridDim.y;
    int id = blockIdx.y * gx + blockIdx.x;
    int swz = (id & 7) * (nwg >> 3) + (id >> 3);
    int bm = swz / gx, bn = swz % gx;
    int m0 = bm * 256, n0 = bn * 256;
    int kstart = blockIdx.z * kLen;
    int rem = Ktot - kstart;
    int nt = ((rem < kLen) ? rem : kLen) >> 6;

    const unsigned short* At = A + (size_t)m0 * lda + kstart;
    const unsigned short* Bt = B + (size_t)n0 * ldb + kstart;

    // prologue: tile0 full + Aa(1), Bg(1); then vmcnt(4)
    stageA(lds[0][0], At, lda, 0, wid, lane);
    stageA(lds[0][0], At, lda, 1, wid, lane);
    stageB(lds[0][1], Bt, ldb, 0, wid, lane);
    stageB(lds[0][1], Bt, ldb, 1, wid, lane);
    int k1 = (nt > 1) ? 64 : 0;
    stageA(lds[1][0], At + k1, lda, 0, wid, lane);
    stageB(lds[1][1], Bt + k1, ldb, 0, wid, lane);
    asm volatile("s_waitcnt vmcnt(4)" ::: "memory");
    __builtin_amdgcn_s_barrier();

    f32x4 acc[8][4] = {};
    bf16x8 afT[2][4], afB[2][4], bL[2][2], bR[2][2];

    for (int u = 0; u < nt; u++) {
        int buf = u & 1;
        const unsigned short (*LA)[64] = lds[buf][0];
        const unsigned short (*LB)[64] = lds[buf][1];
        int t1 = (u + 1 < nt) ? u + 1 : nt - 1;
        int t2 = (u + 2 < nt) ? u + 2 : nt - 1;

        // ---- ph1: A-top + B-left -> Q00
        loadA(LA, afT, 0, wr, lo, hi);
        loadB(LB, bL, 0, wc, lo, hi);
        stageA(lds[buf ^ 1][0], At + t1 * 64, lda, 1, wid, lane);   // Ab(t1)
        PH_SYNC();
        __builtin_amdgcn_s_setprio(1);
        mfma16<0, 0>(bL, afT, acc);
        __builtin_amdgcn_s_setprio(0);
        __builtin_amdgcn_s_barrier();

        // ---- ph2: B-right -> Q01 (A-top reused)
        loadB(LB, bR, 1, wc, lo, hi);
        stageB(lds[buf ^ 1][1], Bt + t1 * 64, ldb, 1, wid, lane);   // Bd(t1)
        PH_SYNC();
        __builtin_amdgcn_s_setprio(1);
        mfma16<0, 1>(bR, afT, acc);
        __builtin_amdgcn_s_setprio(0);
        __builtin_amdgcn_s_barrier();

        // ---- ph3: A-bot -> Q11; Q10 register-only; counted vmcnt
        loadA(LA, afB, 1, wr, lo, hi);
        stageA(lds[buf][0], At + t2 * 64, lda, 0, wid, lane);       // Aa(t2)
        PH_SYNC();
        __builtin_amdgcn_s_setprio(1);
        mfma16<1, 1>(bR, afB, acc);
        stageB(lds[buf][1], Bt + t2 * 64, ldb, 0, wid, lane);       // Bg(t2)
        mfma16<1, 0>(bL, afB, acc);
        __builtin_amdgcn_s_setprio(0);
        asm volatile("s_waitcnt vmcnt(4)" ::: "memory");
        __builtin_amdgcn_s_barrier();
    }

    // ---- epilogue ----  acc[ri][ci][j]: row M = m0+wr*128+ri*16+lo,
    //                     col N = n0+wc*64+ci*16+hi*4+j  (j contiguous in N)
    if (MODE == 0) {
        float* po = (blockIdx.z < 2)
            ? (float*)outp    + (size_t)blockIdx.z       * SQ * (size_t)N
            : (float*)outp_hi + (size_t)(blockIdx.z - 2) * SQ * (size_t)N;
        #pragma unroll
        for (int ri = 0; ri < 8; ri++) {
            int gr = m0 + wr * 128 + ri * 16 + lo;
            #pragma unroll
            for (int ci = 0; ci < 4; ci++) {
                int gc = n0 + wc * 64 + ci * 16 + hi * 4;
                *(f32x4*)&po[(size_t)gr * N + gc] = acc[ri][ci];
            }
        }
    } else if (MODE == 1) {
        unsigned short* op = (unsigned short*)outp;
        #pragma unroll
        for (int ri = 0; ri < 8; ri++) {
            int gr = m0 + wr * 128 + ri * 16 + lo;
            #pragma unroll
            for (int ci = 0; ci < 4; ci++) {
                int gc = n0 + wc * 64 + ci * 16 + hi * 4;
                float4 bi = *(const float4*)&bias[gc];
                float v0 = acc[ri][ci][0] + bi.x, v1 = acc[ri][ci][1] + bi.y;
                float v2 = acc[ri][ci][2] + bi.z, v3 = acc[ri][ci][3] + bi.w;
                if (GELU_ON) { v0 = gelu_f(v0); v1 = gelu_f(v1); v2 = gelu_f(v2); v3 = gelu_f(v3); }
                ushort4 o; o.x = f2bf(v0); o.y = f2bf(v1); o.z = f2bf(v2); o.w = f2bf(v3);
                *(ushort4*)&op[(size_t)gr * N + gc] = o;
            }
        }
    } else {
        unsigned short* op = (unsigned short*)outp;
        #pragma unroll
        for (int ri = 0; ri < 8; ri++) {
            int gr = m0 + wr * 128 + ri * 16 + lo;
            #pragma unroll
            for (int ci = 0; ci < 4; ci++) {
                int gc = n0 + wc * 64 + ci * 16 + hi * 4;
                int head = gc / 384;
                int within = gc - head * 384;
                float4 bi = *(const float4*)&bias[gc];
                float v0 = acc[ri][ci][0] + bi.x, v1 = acc[ri][ci][1] + bi.y;
                float v2 = acc[ri][ci][2] + bi.z, v3 = acc[ri][ci][3] + bi.w;
                if (within >= 256) {        // V columns -> transposed store
                    int d = within - 256;
                    unsigned short* vp = vtb + (size_t)(head * HD + d) * SQ + gr;
                    vp[0]          = f2bf(v0);
                    vp[SQ]         = f2bf(v1);
                    vp[2 * SQ]     = f2bf(v2);
                    vp[3 * SQ]     = f2bf(v3);
                } else {
                    ushort4 o; o.x = f2bf(v0); o.y = f2bf(v1); o.z = f2bf(v2); o.w = f2bf(v3);
                    *(ushort4*)&op[(size_t)gr * N + gc] = o;
                }
            }
        }
    }
}

// ---------------- Flash attention: 32x32 MFMA, causal + alibi ----------------
__global__ __launch_bounds__(128) void attn_kernel(
    const unsigned short* __restrict__ qkvB,  // [S][6144] bf16 (q,k valid)
    const unsigned short* __restrict__ vtb,   // [NH][HD][S] bf16
    unsigned short* __restrict__ ctx)         // [S][2048] bf16
{
    int w = blockIdx.x;
    int lid = (w & 7) * 64 + (w >> 3);
    int n = lid >> 5, qt = lid & 31;
    int t = threadIdx.x, lane = t & 63, wid = t >> 6;
    int l32 = lane & 31, h2 = lane >> 5;
    int q0 = qt * 64, qg = q0 + wid * 32 + l32;

    __shared__ __align__(16) unsigned short Ks[64][128];
    __shared__ __align__(16) unsigned short Vt[128][64];

    bf16x8 qf[8];
    const unsigned short* qp = qkvB + (size_t)qg * QKVW + n * 384 + h2 * 8;
    #pragma unroll
    for (int d8 = 0; d8 < 8; d8++)
        qf[d8] = *(const bf16x8*)(qp + d8 * 16);

    const float slope = exp2f(-0.5f * (float)(n + 1));
    const float inv = 0.08838834764831845f;   // 1/sqrt(128)
    float m = -INFINITY, lsum = 0.f;
    f32x16 ao[4] = {};

    int krow = lane >> 4, kch = lane & 15;
    int vrow = lane >> 3, vch = lane & 7;
    const unsigned short* kb_ = qkvB + n * 384 + 128;
    const unsigned short* vb_ = vtb + (size_t)n * HD * SQ;
    const char* ksb = (const char*)&Ks[0][0];
    const char* vsb = (const char*)&Vt[0][0];

    int nkb = qt + 1;
    for (int kb = 0; kb < nkb; kb++) {
        int k0 = kb * 64;
        __syncthreads();
        #pragma unroll
        for (int s = 0; s < 8; s++) {
            int r = wid * 32 + s * 4 + krow;
            gld16(&Ks[wid * 32 + s * 4][0],
                  kb_ + (size_t)(k0 + r) * QKVW + ((kch ^ (r & 7)) << 3));
            int dd = wid * 64 + s * 8 + vrow;
            gld16(&Vt[wid * 64 + s * 8][0],
                  vb_ + (size_t)dd * SQ + k0 + ((vch ^ (dd & 7)) << 3));
        }
        __syncthreads();

        f32x16 sc0 = {}, sc1 = {};
        #pragma unroll
        for (int d8 = 0; d8 < 8; d8++) {
            int ch = ((d8 * 2 + h2) ^ (l32 & 7)) << 4;
            bf16x8 kf0 = *(const bf16x8*)(ksb + l32 * 256 + ch);
            bf16x8 kf1 = *(const bf16x8*)(ksb + (32 + l32) * 256 + ch);
            sc0 = __builtin_amdgcn_mfma_f32_32x32x16_bf16(kf0, qf[d8], sc0, 0, 0, 0);
            sc1 = __builtin_amdgcn_mfma_f32_32x32x16_bf16(kf1, qf[d8], sc1, 0, 0, 0);
        }

        float tmax = -INFINITY;
        int last = (kb == nkb - 1);
        #pragma unroll
        for (int r = 0; r < 16; r++) {
            int kl = (r & 3) + 8 * (r >> 2) + 4 * h2;
            float s0 = sc0[r] * inv + slope * (float)(k0 + kl);
            float s1 = sc1[r] * inv + slope * (float)(k0 + 32 + kl);
            if (last) {
                if (k0 + kl > qg) s0 = -INFINITY;
                if (k0 + 32 + kl > qg) s1 = -INFINITY;
            }
            sc0[r] = s0; sc1[r] = s1;
            tmax = fmaxf(tmax, fmaxf(s0, s1));
        }
        tmax = fmaxf(tmax, __shfl_xor(tmax, 32));
        if (!__all(tmax <= m + 8.f)) {          // defer-max (T13)
            float mnew = fmaxf(m, tmax);
            float sca = __expf(m - mnew);
            m = mnew;
            lsum *= sca;
            #pragma unroll
            for (int db = 0; db < 4; db++)
                #pragma unroll
                for (int e = 0; e < 16; e++) ao[db][e] *= sca;
        }
        float psum = 0.f;
        #pragma unroll
        for (int r = 0; r < 16; r++) {
            sc0[r] = __expf(sc0[r] - m); psum += sc0[r];
            sc1[r] = __expf(sc1[r] - m); psum += sc1[r];
        }
        psum += __shfl_xor(psum, 32);
        lsum += psum;

        #pragma unroll
        for (int kstep = 0; kstep < 4; kstep++) {
            const int ks1 = kstep & 1;
            float a0, a1, a2, a3, b0, b1, b2, b3;
            if (kstep < 2) {
                a0 = sc0[8*ks1+0]; a1 = sc0[8*ks1+1]; a2 = sc0[8*ks1+2]; a3 = sc0[8*ks1+3];
                b0 = sc0[8*ks1+4]; b1 = sc0[8*ks1+5]; b2 = sc0[8*ks1+6]; b3 = sc0[8*ks1+7];
            } else {
                a0 = sc1[8*ks1+0]; a1 = sc1[8*ks1+1]; a2 = sc1[8*ks1+2]; a3 = sc1[8*ks1+3];
                b0 = sc1[8*ks1+4]; b1 = sc1[8*ks1+5]; b2 = sc1[8*ks1+6]; b3 = sc1[8*ks1+7];
            }
            unsigned ku0 = pack_bf2(h2 ? b0 : a0, h2 ? b1 : a1);
            unsigned ku1 = pack_bf2(h2 ? b2 : a2, h2 ? b3 : a3);
            unsigned su0 = pack_bf2(h2 ? a0 : b0, h2 ? a1 : b1);
            unsigned su1 = pack_bf2(h2 ? a2 : b2, h2 ? a3 : b3);
            unsigned r0 = (unsigned)__shfl_xor((int)su0, 32);
            unsigned r1 = (unsigned)__shfl_xor((int)su1, 32);
            union { int4 i; bf16x8 v; } u;
            u.i.x = h2 ? (int)r0  : (int)ku0;
            u.i.y = h2 ? (int)r1  : (int)ku1;
            u.i.z = h2 ? (int)ku0 : (int)r0;
            u.i.w = h2 ? (int)ku1 : (int)r1;
            bf16x8 pf = u.v;
            int ch = ((kstep * 2 + h2) ^ (l32 & 7)) << 4;
            #pragma unroll
            for (int db = 0; db < 4; db++) {
                bf16x8 vf = *(const bf16x8*)(vsb + (db * 32 + l32) * 128 + ch);
                ao[db] = __builtin_amdgcn_mfma_f32_32x32x16_bf16(vf, pf, ao[db], 0, 0, 0);
            }
        }
    }

    float rl = 1.f / lsum;
    #pragma unroll
    for (int db = 0; db < 4; db++)
        #pragma unroll
        for (int g = 0; g < 4; g++) {
            ushort4 o;
            o.x = f2bf(ao[db][g*4+0] * rl);
            o.y = f2bf(ao[db][g*4+1] * rl);
            o.z = f2bf(ao[db][g*4+2] * rl);
            o.w = f2bf(ao[db][g*4+3] * rl);
            *(ushort4*)(ctx + (size_t)qg * HH + n * HD + db * 32 + g * 8 + h2 * 4) = o;
        }
}

extern "C" void kernel_launch(void* const* d_in, const int* in_sizes, int n_in,
                              void* d_out, int out_size, void* d_ws, size_t ws_size,
                              hipStream_t stream) {
    const float* hs    = (const float*)d_in[0];
    const float* ln1g  = (const float*)d_in[4];
    const float* ln1b  = (const float*)d_in[5];
    const float* qkvw  = (const float*)d_in[6];
    const float* qkvb  = (const float*)d_in[7];
    const float* dw    = (const float*)d_in[8];
    const float* db    = (const float*)d_in[9];
    const float* ln2g  = (const float*)d_in[10];
    const float* ln2b  = (const float*)d_in[11];
    const float* f1w   = (const float*)d_in[12];
    const float* f1b   = (const float*)d_in[13];
    const float* f2w   = (const float*)d_in[14];
    const float* f2b   = (const float*)d_in[15];
    float* out = (float*)d_out;

    char* ws = (char*)d_ws;
    size_t off = 0;
    auto alloc = [&](size_t nbytes) {
        void* p = ws + off; off += (nbytes + 255) & ~(size_t)255; return p;
    };
    unsigned short* xbf  = (unsigned short*)alloc((size_t)SQ * HH * 2);        // [0, 8.4M)
    unsigned short* qkvB = (unsigned short*)alloc((size_t)SQ * QKVW * 2);      // [8.4M, 33.6M)
    unsigned short* vtB  = (unsigned short*)alloc((size_t)NHEAD * HD * SQ * 2);// [33.6M, 41.9M)
    unsigned short* ctx  = (unsigned short*)alloc((size_t)SQ * HH * 2);        // [41.9M, 50.3M)
    float*          attn = (float*)alloc((size_t)SQ * HH * 4);                 // [50.3M, 67.1M)
    unsigned short* y    = (unsigned short*)alloc((size_t)SQ * HH * 2);        // [67.1M, 75.5M)
    unsigned short* hdn  = (unsigned short*)alloc((size_t)SQ * 4 * HH * 2);    // [75.5M, 109.1M)
    unsigned short* wbuf = (unsigned short*)alloc((size_t)4 * HH * HH * 2);    // [109.1M, 142.6M)

    const size_t PQ = (size_t)SQ * HH;      // floats per partial (16.8 MB)
    float* part = (float*)ws;               // partials 0..2 overlap dead xbf/qkvB/vtB/ctx

    ln_kernel<<<SQ, 256, 0, stream>>>(hs, ln1g, ln1b, xbf);

    cvt_kernel<<<2048, 256, 0, stream>>>(qkvw, wbuf, QKVW * HH / 4);
    gemm256<2, 0><<<dim3(QKVW / 256, SQ / 256, 1), 512, 0, stream>>>(
        xbf, wbuf, qkvb, qkvB, vtB, nullptr, QKVW, HH, HH, HH, HH);

    attn_kernel<<<512, 128, 0, stream>>>(qkvB, vtB, ctx);

    // dense: split-K x4 (256 blocks); partials p0,p1 at ws; p2,p3 in dead hdn
    cvt_kernel<<<1024, 256, 0, stream>>>(dw, wbuf, HH * HH / 4);
    gemm256<0, 0><<<dim3(HH / 256, SQ / 256, 4), 512, 0, stream>>>(
        ctx, wbuf, nullptr, part, nullptr, hdn, HH, HH, HH, HH / 4, HH);
    reduceN_kernel<4><<<2048, 256, 0, stream>>>(
        part, part + PQ, (float*)hdn, (float*)hdn + PQ, hs, db, attn, SQ * HH / 4, HH / 4 - 1);

    ln_kernel<<<SQ, 256, 0, stream>>>(attn, ln2g, ln2b, y);

    cvt_kernel<<<2048, 256, 0, stream>>>(f1w, wbuf, 4 * HH * HH / 4);
    gemm256<1, 1><<<dim3(4 * HH / 256, SQ / 256, 1), 512, 0, stream>>>(
        y, wbuf, f1b, hdn, nullptr, nullptr, 4 * HH, HH, HH, HH, HH);

    // FC2: split-K x3 (192 blocks, kLen=2752=43 tiles); partials at ws[0,50.3M)
    cvt_kernel<<<2048, 256, 0, stream>>>(f2w, wbuf, 4 * HH * HH / 4);
    gemm256<0, 0><<<dim3(HH / 256, SQ / 256, 3), 512, 0, stream>>>(
        hdn, wbuf, nullptr, part, nullptr, part + 2 * PQ, HH, 4 * HH, 4 * HH, 2752, 4 * HH);
    reduceN_kernel<3><<<2048, 256, 0, stream>>>(
        part, part + PQ, part + 2 * PQ, nullptr, attn, f2b, out, SQ * HH / 4, HH / 4 - 1);
}

// Round 6
// 491.083 us; speedup vs baseline: 1.6884x; 1.0023x over previous
//
#include <hip/hip_runtime.h>
#include <hip/hip_bf16.h>

#define SQ 2048
#define HH 2048
#define NHEAD 16
#define HD 128
#define QKVW (NHEAD*3*HD)   // 6144

typedef __attribute__((ext_vector_type(8))) short bf16x8;
typedef __attribute__((ext_vector_type(4))) float f32x4;
typedef __attribute__((ext_vector_type(16))) float f32x16;

__device__ inline unsigned short f2bf(float f) {
    union { float f; unsigned u; } x; x.f = f;
    unsigned r = x.u + 0x7FFFu + ((x.u >> 16) & 1u);
    return (unsigned short)(r >> 16);
}

__device__ inline unsigned pack_bf2(float a, float b) {
    return (unsigned)f2bf(a) | ((unsigned)f2bf(b) << 16);
}

__device__ inline float gelu_f(float x) {
    float x3 = x * (1.f + 0.044715f * x * x);
    return 0.5f * x * (1.f + tanhf(0.79788456f * x3));
}

// async global->LDS, 16B per lane. lds must be wave-uniform; g is per-lane.
__device__ inline void gld16(void* lds, const void* g) {
    __builtin_amdgcn_global_load_lds(
        (__attribute__((address_space(1))) void*)(g),
        (__attribute__((address_space(3))) void*)(lds), 16, 0, 0);
}

// ---------------- fp32 -> bf16 convert ----------------
__global__ __launch_bounds__(256) void cvt_kernel(
    const float* __restrict__ in, unsigned short* __restrict__ out, int n4)
{
    int i = blockIdx.x * blockDim.x + threadIdx.x;
    int stride = gridDim.x * blockDim.x;
    for (; i < n4; i += stride) {
        float4 f = ((const float4*)in)[i];
        ushort4 o;
        o.x = f2bf(f.x); o.y = f2bf(f.y); o.z = f2bf(f.z); o.w = f2bf(f.w);
        ((ushort4*)out)[i] = o;
    }
}

// ---------------- LayerNorm: fp32 in -> bf16 out ----------------
__global__ __launch_bounds__(256) void ln_kernel(
    const float* __restrict__ in, const float* __restrict__ g,
    const float* __restrict__ b, unsigned short* __restrict__ out)
{
    int row = blockIdx.x;
    int t = threadIdx.x, lane = t & 63, wid = t >> 6;
    const float4* rp = (const float4*)(in + (size_t)row * HH);
    float4 v0 = rp[t], v1 = rp[t + 256];
    float s  = v0.x + v0.y + v0.z + v0.w + v1.x + v1.y + v1.z + v1.w;
    float ss = v0.x*v0.x + v0.y*v0.y + v0.z*v0.z + v0.w*v0.w
             + v1.x*v1.x + v1.y*v1.y + v1.z*v1.z + v1.w*v1.w;
    #pragma unroll
    for (int o = 32; o; o >>= 1) { s += __shfl_down(s, o); ss += __shfl_down(ss, o); }
    __shared__ float r0[4], r1[4];
    if (lane == 0) { r0[wid] = s; r1[wid] = ss; }
    __syncthreads();
    s  = r0[0] + r0[1] + r0[2] + r0[3];
    ss = r1[0] + r1[1] + r1[2] + r1[3];
    float mu = s * (1.f / HH);
    float var = ss * (1.f / HH) - mu * mu;
    float rs = rsqrtf(var + 1e-5f);
    float4 g0 = ((const float4*)g)[t], g1 = ((const float4*)g)[t + 256];
    float4 b0 = ((const float4*)b)[t], b1 = ((const float4*)b)[t + 256];
    ushort4 o0, o1;
    o0.x = f2bf((v0.x - mu) * rs * g0.x + b0.x);
    o0.y = f2bf((v0.y - mu) * rs * g0.y + b0.y);
    o0.z = f2bf((v0.z - mu) * rs * g0.z + b0.z);
    o0.w = f2bf((v0.w - mu) * rs * g0.w + b0.w);
    o1.x = f2bf((v1.x - mu) * rs * g1.x + b1.x);
    o1.y = f2bf((v1.y - mu) * rs * g1.y + b1.y);
    o1.z = f2bf((v1.z - mu) * rs * g1.z + b1.z);
    o1.w = f2bf((v1.w - mu) * rs * g1.w + b1.w);
    ushort4* op = (ushort4*)(out + (size_t)row * HH);
    op[t] = o0; op[t + 256] = o1;
}

// ---------------- reduce: out = sum(partials) + res + bias ----------------
template<int NP>
__global__ __launch_bounds__(256) void reduceN_kernel(
    const float* __restrict__ p0, const float* __restrict__ p1,
    const float* __restrict__ p2, const float* __restrict__ p3,
    const float* __restrict__ res, const float* __restrict__ bias,
    float* __restrict__ out, int n4, int nc4m1)
{
    int i = blockIdx.x * blockDim.x + threadIdx.x;
    int st = gridDim.x * blockDim.x;
    for (; i < n4; i += st) {
        float4 a = ((const float4*)p0)[i];
        float4 b = ((const float4*)p1)[i];
        float4 r = ((const float4*)res)[i];
        float4 bv = ((const float4*)bias)[i & nc4m1];
        float4 o;
        o.x = a.x + b.x + r.x + bv.x;
        o.y = a.y + b.y + r.y + bv.y;
        o.z = a.z + b.z + r.z + bv.z;
        o.w = a.w + b.w + r.w + bv.w;
        if (NP >= 3) {
            float4 c = ((const float4*)p2)[i];
            o.x += c.x; o.y += c.y; o.z += c.z; o.w += c.w;
        }
        if (NP >= 4) {
            float4 d = ((const float4*)p3)[i];
            o.x += d.x; o.y += d.y; o.z += d.z; o.w += d.w;
        }
        ((float4*)out)[i] = o;
    }
}

// =============== 256x256 3-phase GEMM (T1..T5, frag-reuse) ===============
// C[M,N] = A[M,K]bf16 @ B[N,K]bf16^T. BK=64, 512 thr = 8 waves (2Mx4N),
// per-wave C 128x64. LDS 2buf x (A 256x64 + B 256x64), chunk-XOR swizzle.
// Per tile: ph1 {read A-top+B-left -> Q00}, ph2 {read B-right -> Q01},
// ph3 {read A-bot -> Q11; Q10 reg-only; counted vmcnt(4)}. 24 b128/wave/tile.
// MFMA operand-swapped: acc = mfma(b,a) -> lane cols = M, regs = N (vec stores).
// XCD mapping: 2D chunked (CH x CW tile rectangle per XCD) so co-resident
// blocks of one XCD share A/B K-slices in that XCD's L2 (sliding window).

__device__ __forceinline__ void stageA(unsigned short (*dst)[64],
    const unsigned short* Abase, int ld, int h, int wid, int lane)
{
    int rb = (wid >> 2) * 128 + h * 64 + (wid & 3) * 16;
    #pragma unroll
    for (int j = 0; j < 2; j++) {
        int r = rb + j * 8 + (lane >> 3);
        int ch = (lane & 7) ^ (r & 7);
        gld16(&dst[rb + j * 8][0], Abase + (size_t)r * ld + ch * 8);
    }
}

__device__ __forceinline__ void stageB(unsigned short (*dst)[64],
    const unsigned short* Bbase, int ld, int h, int wid, int lane)
{
    int rb = (wid >> 1) * 64 + h * 32 + (wid & 1) * 16;
    #pragma unroll
    for (int j = 0; j < 2; j++) {
        int r = rb + j * 8 + (lane >> 3);
        int ch = (lane & 7) ^ (r & 7);
        gld16(&dst[rb + j * 8][0], Bbase + (size_t)r * ld + ch * 8);
    }
}

__device__ __forceinline__ void loadA(const unsigned short (*ldsA)[64],
    bf16x8 (&af)[2][4], int half, int wr, int lo, int hi)
{
    #pragma unroll
    for (int ks = 0; ks < 2; ks++) {
        int g = ks * 4 + hi;
        #pragma unroll
        for (int i = 0; i < 4; i++) {
            int r = wr * 128 + half * 64 + i * 16 + lo;
            af[ks][i] = *(const bf16x8*)&ldsA[r][(g ^ (r & 7)) << 3];
        }
    }
}

__device__ __forceinline__ void loadB(const unsigned short (*ldsB)[64],
    bf16x8 (&bf)[2][2], int half, int wc, int lo, int hi)
{
    #pragma unroll
    for (int ks = 0; ks < 2; ks++) {
        int g = ks * 4 + hi;
        #pragma unroll
        for (int c = 0; c < 2; c++) {
            int r = wc * 64 + half * 32 + c * 16 + lo;
            bf[ks][c] = *(const bf16x8*)&ldsB[r][(g ^ (r & 7)) << 3];
        }
    }
}

template<int QR, int QC>
__device__ __forceinline__ void mfma16(
    const bf16x8 (&bf)[2][2], const bf16x8 (&af)[2][4], f32x4 (&acc)[8][4])
{
    #pragma unroll
    for (int ks = 0; ks < 2; ks++)
        #pragma unroll
        for (int i = 0; i < 4; i++)
            #pragma unroll
            for (int c = 0; c < 2; c++)
                acc[QR*4+i][QC*2+c] = __builtin_amdgcn_mfma_f32_16x16x32_bf16(
                    bf[ks][c], af[ks][i], acc[QR*4+i][QC*2+c], 0, 0, 0);
}

#define PH_SYNC() do { \
    __builtin_amdgcn_s_barrier(); \
    asm volatile("s_waitcnt lgkmcnt(0)" ::: "memory"); \
    __builtin_amdgcn_sched_barrier(0); \
} while (0)

// MODE: 0 = fp32 partial (no bias), 1 = bf16 + bias (+GELU), 2 = QKV splitV
template<int MODE, int GELU_ON>
__global__ __launch_bounds__(512, 2) void gemm256(
    const unsigned short* __restrict__ A, const unsigned short* __restrict__ B,
    const float* __restrict__ bias, void* __restrict__ outp,
    unsigned short* __restrict__ vtb, void* __restrict__ outp_hi,
    int N, int lda, int ldb, int kLen, int Ktot, int CH, int CW)
{
    __shared__ unsigned short lds[2][2][256][64];   // 128 KiB

    int t = threadIdx.x, lane = t & 63, wid = t >> 6;
    int lo = lane & 15, hi = lane >> 4;
    int wr = wid >> 2, wc = wid & 3;

    // 2D chunked XCD swizzle over the (R = bz*gy+by, bx) tile grid.
    // id%8 = XCD (round-robin dispatch). XCD gets a CH x CW rectangle.
    int id = (blockIdx.z * gridDim.y + blockIdx.y) * gridDim.x + blockIdx.x;
    int xcd = id & 7, local = id >> 3;
    int cgx = gridDim.x / CW;                 // chunk-grid cols
    int cr = xcd / cgx, cc = xcd - cr * cgx;  // chunk position
    int lr = local / CW, lc = local - lr * CW;
    int R  = cr * CH + lr;
    int bn = cc * CW + lc;
    int bm = R % gridDim.y;
    int bz = R / gridDim.y;
    int m0 = bm * 256, n0 = bn * 256;
    int kstart = bz * kLen;
    int rem = Ktot - kstart;
    int nt = ((rem < kLen) ? rem : kLen) >> 6;

    const unsigned short* At = A + (size_t)m0 * lda + kstart;
    const unsigned short* Bt = B + (size_t)n0 * ldb + kstart;

    // prologue: tile0 full + Aa(1), Bg(1); then vmcnt(4)
    stageA(lds[0][0], At, lda, 0, wid, lane);
    stageA(lds[0][0], At, lda, 1, wid, lane);
    stageB(lds[0][1], Bt, ldb, 0, wid, lane);
    stageB(lds[0][1], Bt, ldb, 1, wid, lane);
    int k1 = (nt > 1) ? 64 : 0;
    stageA(lds[1][0], At + k1, lda, 0, wid, lane);
    stageB(lds[1][1], Bt + k1, ldb, 0, wid, lane);
    asm volatile("s_waitcnt vmcnt(4)" ::: "memory");
    __builtin_amdgcn_s_barrier();

    f32x4 acc[8][4] = {};
    bf16x8 afT[2][4], afB[2][4], bL[2][2], bR[2][2];

    for (int u = 0; u < nt; u++) {
        int buf = u & 1;
        const unsigned short (*LA)[64] = lds[buf][0];
        const unsigned short (*LB)[64] = lds[buf][1];
        int t1 = (u + 1 < nt) ? u + 1 : nt - 1;
        int t2 = (u + 2 < nt) ? u + 2 : nt - 1;

        // ---- ph1: A-top + B-left -> Q00
        loadA(LA, afT, 0, wr, lo, hi);
        loadB(LB, bL, 0, wc, lo, hi);
        stageA(lds[buf ^ 1][0], At + t1 * 64, lda, 1, wid, lane);   // Ab(t1)
        PH_SYNC();
        __builtin_amdgcn_s_setprio(1);
        mfma16<0, 0>(bL, afT, acc);
        __builtin_amdgcn_s_setprio(0);
        __builtin_amdgcn_s_barrier();

        // ---- ph2: B-right -> Q01 (A-top reused)
        loadB(LB, bR, 1, wc, lo, hi);
        stageB(lds[buf ^ 1][1], Bt + t1 * 64, ldb, 1, wid, lane);   // Bd(t1)
        PH_SYNC();
        __builtin_amdgcn_s_setprio(1);
        mfma16<0, 1>(bR, afT, acc);
        __builtin_amdgcn_s_setprio(0);
        __builtin_amdgcn_s_barrier();

        // ---- ph3: A-bot -> Q11; Q10 register-only; counted vmcnt
        loadA(LA, afB, 1, wr, lo, hi);
        stageA(lds[buf][0], At + t2 * 64, lda, 0, wid, lane);       // Aa(t2)
        PH_SYNC();
        __builtin_amdgcn_s_setprio(1);
        mfma16<1, 1>(bR, afB, acc);
        stageB(lds[buf][1], Bt + t2 * 64, ldb, 0, wid, lane);       // Bg(t2)
        mfma16<1, 0>(bL, afB, acc);
        __builtin_amdgcn_s_setprio(0);
        asm volatile("s_waitcnt vmcnt(4)" ::: "memory");
        __builtin_amdgcn_s_barrier();
    }

    // ---- epilogue ----  acc[ri][ci][j]: row M = m0+wr*128+ri*16+lo,
    //                     col N = n0+wc*64+ci*16+hi*4+j  (j contiguous in N)
    if (MODE == 0) {
        float* po = (bz < 2)
            ? (float*)outp    + (size_t)bz       * SQ * (size_t)N
            : (float*)outp_hi + (size_t)(bz - 2) * SQ * (size_t)N;
        #pragma unroll
        for (int ri = 0; ri < 8; ri++) {
            int gr = m0 + wr * 128 + ri * 16 + lo;
            #pragma unroll
            for (int ci = 0; ci < 4; ci++) {
                int gc = n0 + wc * 64 + ci * 16 + hi * 4;
                *(f32x4*)&po[(size_t)gr * N + gc] = acc[ri][ci];
            }
        }
    } else if (MODE == 1) {
        unsigned short* op = (unsigned short*)outp;
        #pragma unroll
        for (int ri = 0; ri < 8; ri++) {
            int gr = m0 + wr * 128 + ri * 16 + lo;
            #pragma unroll
            for (int ci = 0; ci < 4; ci++) {
                int gc = n0 + wc * 64 + ci * 16 + hi * 4;
                float4 bi = *(const float4*)&bias[gc];
                float v0 = acc[ri][ci][0] + bi.x, v1 = acc[ri][ci][1] + bi.y;
                float v2 = acc[ri][ci][2] + bi.z, v3 = acc[ri][ci][3] + bi.w;
                if (GELU_ON) { v0 = gelu_f(v0); v1 = gelu_f(v1); v2 = gelu_f(v2); v3 = gelu_f(v3); }
                ushort4 o; o.x = f2bf(v0); o.y = f2bf(v1); o.z = f2bf(v2); o.w = f2bf(v3);
                *(ushort4*)&op[(size_t)gr * N + gc] = o;
            }
        }
    } else {
        unsigned short* op = (unsigned short*)outp;
        #pragma unroll
        for (int ri = 0; ri < 8; ri++) {
            int gr = m0 + wr * 128 + ri * 16 + lo;
            #pragma unroll
            for (int ci = 0; ci < 4; ci++) {
                int gc = n0 + wc * 64 + ci * 16 + hi * 4;
                int head = gc / 384;
                int within = gc - head * 384;
                float4 bi = *(const float4*)&bias[gc];
                float v0 = acc[ri][ci][0] + bi.x, v1 = acc[ri][ci][1] + bi.y;
                float v2 = acc[ri][ci][2] + bi.z, v3 = acc[ri][ci][3] + bi.w;
                if (within >= 256) {        // V columns -> transposed store
                    int d = within - 256;
                    unsigned short* vp = vtb + (size_t)(head * HD + d) * SQ + gr;
                    vp[0]          = f2bf(v0);
                    vp[SQ]         = f2bf(v1);
                    vp[2 * SQ]     = f2bf(v2);
                    vp[3 * SQ]     = f2bf(v3);
                } else {
                    ushort4 o; o.x = f2bf(v0); o.y = f2bf(v1); o.z = f2bf(v2); o.w = f2bf(v3);
                    *(ushort4*)&op[(size_t)gr * N + gc] = o;
                }
            }
        }
    }
}

// ---------------- Flash attention: 32x32 MFMA, causal + alibi ----------------
__global__ __launch_bounds__(128) void attn_kernel(
    const unsigned short* __restrict__ qkvB,  // [S][6144] bf16 (q,k valid)
    const unsigned short* __restrict__ vtb,   // [NH][HD][S] bf16
    unsigned short* __restrict__ ctx)         // [S][2048] bf16
{
    int w = blockIdx.x;
    int lid = (w & 7) * 64 + (w >> 3);
    int n = lid >> 5, qt = lid & 31;
    int t = threadIdx.x, lane = t & 63, wid = t >> 6;
    int l32 = lane & 31, h2 = lane >> 5;
    int q0 = qt * 64, qg = q0 + wid * 32 + l32;

    __shared__ __align__(16) unsigned short Ks[64][128];
    __shared__ __align__(16) unsigned short Vt[128][64];

    bf16x8 qf[8];
    const unsigned short* qp = qkvB + (size_t)qg * QKVW + n * 384 + h2 * 8;
    #pragma unroll
    for (int d8 = 0; d8 < 8; d8++)
        qf[d8] = *(const bf16x8*)(qp + d8 * 16);

    const float slope = exp2f(-0.5f * (float)(n + 1));
    const float inv = 0.08838834764831845f;   // 1/sqrt(128)
    float m = -INFINITY, lsum = 0.f;
    f32x16 ao[4] = {};

    int krow = lane >> 4, kch = lane & 15;
    int vrow = lane >> 3, vch = lane & 7;
    const unsigned short* kb_ = qkvB + n * 384 + 128;
    const unsigned short* vb_ = vtb + (size_t)n * HD * SQ;
    const char* ksb = (const char*)&Ks[0][0];
    const char* vsb = (const char*)&Vt[0][0];

    int nkb = qt + 1;
    for (int kb = 0; kb < nkb; kb++) {
        int k0 = kb * 64;
        __syncthreads();
        #pragma unroll
        for (int s = 0; s < 8; s++) {
            int r = wid * 32 + s * 4 + krow;
            gld16(&Ks[wid * 32 + s * 4][0],
                  kb_ + (size_t)(k0 + r) * QKVW + ((kch ^ (r & 7)) << 3));
            int dd = wid * 64 + s * 8 + vrow;
            gld16(&Vt[wid * 64 + s * 8][0],
                  vb_ + (size_t)dd * SQ + k0 + ((vch ^ (dd & 7)) << 3));
        }
        __syncthreads();

        f32x16 sc0 = {}, sc1 = {};
        #pragma unroll
        for (int d8 = 0; d8 < 8; d8++) {
            int ch = ((d8 * 2 + h2) ^ (l32 & 7)) << 4;
            bf16x8 kf0 = *(const bf16x8*)(ksb + l32 * 256 + ch);
            bf16x8 kf1 = *(const bf16x8*)(ksb + (32 + l32) * 256 + ch);
            sc0 = __builtin_amdgcn_mfma_f32_32x32x16_bf16(kf0, qf[d8], sc0, 0, 0, 0);
            sc1 = __builtin_amdgcn_mfma_f32_32x32x16_bf16(kf1, qf[d8], sc1, 0, 0, 0);
        }

        float tmax = -INFINITY;
        int last = (kb == nkb - 1);
        #pragma unroll
        for (int r = 0; r < 16; r++) {
            int kl = (r & 3) + 8 * (r >> 2) + 4 * h2;
            float s0 = sc0[r] * inv + slope * (float)(k0 + kl);
            float s1 = sc1[r] * inv + slope * (float)(k0 + 32 + kl);
            if (last) {
                if (k0 + kl > qg) s0 = -INFINITY;
                if (k0 + 32 + kl > qg) s1 = -INFINITY;
            }
            sc0[r] = s0; sc1[r] = s1;
            tmax = fmaxf(tmax, fmaxf(s0, s1));
        }
        tmax = fmaxf(tmax, __shfl_xor(tmax, 32));
        if (!__all(tmax <= m + 8.f)) {          // defer-max (T13)
            float mnew = fmaxf(m, tmax);
            float sca = __expf(m - mnew);
            m = mnew;
            lsum *= sca;
            #pragma unroll
            for (int db = 0; db < 4; db++)
                #pragma unroll
                for (int e = 0; e < 16; e++) ao[db][e] *= sca;
        }
        float psum = 0.f;
        #pragma unroll
        for (int r = 0; r < 16; r++) {
            sc0[r] = __expf(sc0[r] - m); psum += sc0[r];
            sc1[r] = __expf(sc1[r] - m); psum += sc1[r];
        }
        psum += __shfl_xor(psum, 32);
        lsum += psum;

        #pragma unroll
        for (int kstep = 0; kstep < 4; kstep++) {
            const int ks1 = kstep & 1;
            float a0, a1, a2, a3, b0, b1, b2, b3;
            if (kstep < 2) {
                a0 = sc0[8*ks1+0]; a1 = sc0[8*ks1+1]; a2 = sc0[8*ks1+2]; a3 = sc0[8*ks1+3];
                b0 = sc0[8*ks1+4]; b1 = sc0[8*ks1+5]; b2 = sc0[8*ks1+6]; b3 = sc0[8*ks1+7];
            } else {
                a0 = sc1[8*ks1+0]; a1 = sc1[8*ks1+1]; a2 = sc1[8*ks1+2]; a3 = sc1[8*ks1+3];
                b0 = sc1[8*ks1+4]; b1 = sc1[8*ks1+5]; b2 = sc1[8*ks1+6]; b3 = sc1[8*ks1+7];
            }
            unsigned ku0 = pack_bf2(h2 ? b0 : a0, h2 ? b1 : a1);
            unsigned ku1 = pack_bf2(h2 ? b2 : a2, h2 ? b3 : a3);
            unsigned su0 = pack_bf2(h2 ? a0 : b0, h2 ? a1 : b1);
            unsigned su1 = pack_bf2(h2 ? a2 : b2, h2 ? a3 : b3);
            unsigned r0 = (unsigned)__shfl_xor((int)su0, 32);
            unsigned r1 = (unsigned)__shfl_xor((int)su1, 32);
            union { int4 i; bf16x8 v; } u;
            u.i.x = h2 ? (int)r0  : (int)ku0;
            u.i.y = h2 ? (int)r1  : (int)ku1;
            u.i.z = h2 ? (int)ku0 : (int)r0;
            u.i.w = h2 ? (int)ku1 : (int)r1;
            bf16x8 pf = u.v;
            int ch = ((kstep * 2 + h2) ^ (l32 & 7)) << 4;
            #pragma unroll
            for (int db = 0; db < 4; db++) {
                bf16x8 vf = *(const bf16x8*)(vsb + (db * 32 + l32) * 128 + ch);
                ao[db] = __builtin_amdgcn_mfma_f32_32x32x16_bf16(vf, pf, ao[db], 0, 0, 0);
            }
        }
    }

    float rl = 1.f / lsum;
    #pragma unroll
    for (int db = 0; db < 4; db++)
        #pragma unroll
        for (int g = 0; g < 4; g++) {
            ushort4 o;
            o.x = f2bf(ao[db][g*4+0] * rl);
            o.y = f2bf(ao[db][g*4+1] * rl);
            o.z = f2bf(ao[db][g*4+2] * rl);
            o.w = f2bf(ao[db][g*4+3] * rl);
            *(ushort4*)(ctx + (size_t)qg * HH + n * HD + db * 32 + g * 8 + h2 * 4) = o;
        }
}

extern "C" void kernel_launch(void* const* d_in, const int* in_sizes, int n_in,
                              void* d_out, int out_size, void* d_ws, size_t ws_size,
                              hipStream_t stream) {
    const float* hs    = (const float*)d_in[0];
    const float* ln1g  = (const float*)d_in[4];
    const float* ln1b  = (const float*)d_in[5];
    const float* qkvw  = (const float*)d_in[6];
    const float* qkvb  = (const float*)d_in[7];
    const float* dw    = (const float*)d_in[8];
    const float* db    = (const float*)d_in[9];
    const float* ln2g  = (const float*)d_in[10];
    const float* ln2b  = (const float*)d_in[11];
    const float* f1w   = (const float*)d_in[12];
    const float* f1b   = (const float*)d_in[13];
    const float* f2w   = (const float*)d_in[14];
    const float* f2b   = (const float*)d_in[15];
    float* out = (float*)d_out;

    char* ws = (char*)d_ws;
    size_t off = 0;
    auto alloc = [&](size_t nbytes) {
        void* p = ws + off; off += (nbytes + 255) & ~(size_t)255; return p;
    };
    unsigned short* xbf  = (unsigned short*)alloc((size_t)SQ * HH * 2);        // [0, 8.4M)
    unsigned short* qkvB = (unsigned short*)alloc((size_t)SQ * QKVW * 2);      // [8.4M, 33.6M)
    unsigned short* vtB  = (unsigned short*)alloc((size_t)NHEAD * HD * SQ * 2);// [33.6M, 41.9M)
    unsigned short* ctx  = (unsigned short*)alloc((size_t)SQ * HH * 2);        // [41.9M, 50.3M)
    float*          attn = (float*)alloc((size_t)SQ * HH * 4);                 // [50.3M, 67.1M)
    unsigned short* y    = (unsigned short*)alloc((size_t)SQ * HH * 2);        // [67.1M, 75.5M)
    unsigned short* hdn  = (unsigned short*)alloc((size_t)SQ * 4 * HH * 2);    // [75.5M, 109.1M)
    unsigned short* wbuf = (unsigned short*)alloc((size_t)4 * HH * HH * 2);    // [109.1M, 142.6M)

    const size_t PQ = (size_t)SQ * HH;      // floats per partial (16.8 MB)
    float* part = (float*)ws;               // partials 0..2 overlap dead xbf/qkvB/vtB/ctx

    ln_kernel<<<SQ, 256, 0, stream>>>(hs, ln1g, ln1b, xbf);

    cvt_kernel<<<2048, 256, 0, stream>>>(qkvw, wbuf, QKVW * HH / 4);
    gemm256<2, 0><<<dim3(QKVW / 256, SQ / 256, 1), 512, 0, stream>>>(
        xbf, wbuf, qkvb, qkvB, vtB, nullptr, QKVW, HH, HH, HH, HH, 4, 6);

    attn_kernel<<<512, 128, 0, stream>>>(qkvB, vtB, ctx);

    // dense: split-K x4 (256 blocks); partials p0,p1 at ws; p2,p3 in dead hdn
    cvt_kernel<<<1024, 256, 0, stream>>>(dw, wbuf, HH * HH / 4);
    gemm256<0, 0><<<dim3(HH / 256, SQ / 256, 4), 512, 0, stream>>>(
        ctx, wbuf, nullptr, part, nullptr, hdn, HH, HH, HH, HH / 4, HH, 8, 4);
    reduceN_kernel<4><<<2048, 256, 0, stream>>>(
        part, part + PQ, (float*)hdn, (float*)hdn + PQ, hs, db, attn, SQ * HH / 4, HH / 4 - 1);

    ln_kernel<<<SQ, 256, 0, stream>>>(attn, ln2g, ln2b, y);

    cvt_kernel<<<2048, 256, 0, stream>>>(f1w, wbuf, 4 * HH * HH / 4);
    gemm256<1, 1><<<dim3(4 * HH / 256, SQ / 256, 1), 512, 0, stream>>>(
        y, wbuf, f1b, hdn, nullptr, nullptr, 4 * HH, HH, HH, HH, HH, 4, 8);

    // FC2: split-K x3 (192 blocks, kLen=2752=43 tiles); partials at ws[0,50.3M)
    cvt_kernel<<<2048, 256, 0, stream>>>(f2w, wbuf, 4 * HH * HH / 4);
    gemm256<0, 0><<<dim3(HH / 256, SQ / 256, 3), 512, 0, stream>>>(
        hdn, wbuf, nullptr, part, nullptr, part + 2 * PQ, HH, 4 * HH, 4 * HH, 2752, 4 * HH, 6, 4);
    reduceN_kernel<3><<<2048, 256, 0, stream>>>(
        part, part + PQ, part + 2 * PQ, nullptr, attn, f2b, out, SQ * HH / 4, HH / 4 - 1);
}

// Round 7
// 480.794 us; speedup vs baseline: 1.7245x; 1.0214x over previous
//
#include <hip/hip_runtime.h>
#include <hip/hip_bf16.h>

#define SQ 2048
#define HH 2048
#define NHEAD 16
#define HD 128
#define QKVW (NHEAD*3*HD)   // 6144

typedef __attribute__((ext_vector_type(8))) short bf16x8;
typedef __attribute__((ext_vector_type(4))) float f32x4;
typedef __attribute__((ext_vector_type(16))) float f32x16;

__device__ inline unsigned short f2bf(float f) {
    union { float f; unsigned u; } x; x.f = f;
    unsigned r = x.u + 0x7FFFu + ((x.u >> 16) & 1u);
    return (unsigned short)(r >> 16);
}

__device__ inline unsigned pack_bf2(float a, float b) {
    return (unsigned)f2bf(a) | ((unsigned)f2bf(b) << 16);
}

__device__ inline float gelu_f(float x) {
    float x3 = x * (1.f + 0.044715f * x * x);
    return 0.5f * x * (1.f + tanhf(0.79788456f * x3));
}

// async global->LDS, 16B per lane. lds must be wave-uniform; g is per-lane.
__device__ inline void gld16(void* lds, const void* g) {
    __builtin_amdgcn_global_load_lds(
        (__attribute__((address_space(1))) void*)(g),
        (__attribute__((address_space(3))) void*)(lds), 16, 0, 0);
}

// ---------------- fp32 -> bf16 convert ----------------
__global__ __launch_bounds__(256) void cvt_kernel(
    const float* __restrict__ in, unsigned short* __restrict__ out, int n4)
{
    int i = blockIdx.x * blockDim.x + threadIdx.x;
    int stride = gridDim.x * blockDim.x;
    for (; i < n4; i += stride) {
        float4 f = ((const float4*)in)[i];
        ushort4 o;
        o.x = f2bf(f.x); o.y = f2bf(f.y); o.z = f2bf(f.z); o.w = f2bf(f.w);
        ((ushort4*)out)[i] = o;
    }
}

// ---------------- LayerNorm: fp32 in -> bf16 out ----------------
__global__ __launch_bounds__(256) void ln_kernel(
    const float* __restrict__ in, const float* __restrict__ g,
    const float* __restrict__ b, unsigned short* __restrict__ out)
{
    int row = blockIdx.x;
    int t = threadIdx.x, lane = t & 63, wid = t >> 6;
    const float4* rp = (const float4*)(in + (size_t)row * HH);
    float4 v0 = rp[t], v1 = rp[t + 256];
    float s  = v0.x + v0.y + v0.z + v0.w + v1.x + v1.y + v1.z + v1.w;
    float ss = v0.x*v0.x + v0.y*v0.y + v0.z*v0.z + v0.w*v0.w
             + v1.x*v1.x + v1.y*v1.y + v1.z*v1.z + v1.w*v1.w;
    #pragma unroll
    for (int o = 32; o; o >>= 1) { s += __shfl_down(s, o); ss += __shfl_down(ss, o); }
    __shared__ float r0[4], r1[4];
    if (lane == 0) { r0[wid] = s; r1[wid] = ss; }
    __syncthreads();
    s  = r0[0] + r0[1] + r0[2] + r0[3];
    ss = r1[0] + r1[1] + r1[2] + r1[3];
    float mu = s * (1.f / HH);
    float var = ss * (1.f / HH) - mu * mu;
    float rs = rsqrtf(var + 1e-5f);
    float4 g0 = ((const float4*)g)[t], g1 = ((const float4*)g)[t + 256];
    float4 b0 = ((const float4*)b)[t], b1 = ((const float4*)b)[t + 256];
    ushort4 o0, o1;
    o0.x = f2bf((v0.x - mu) * rs * g0.x + b0.x);
    o0.y = f2bf((v0.y - mu) * rs * g0.y + b0.y);
    o0.z = f2bf((v0.z - mu) * rs * g0.z + b0.z);
    o0.w = f2bf((v0.w - mu) * rs * g0.w + b0.w);
    o1.x = f2bf((v1.x - mu) * rs * g1.x + b1.x);
    o1.y = f2bf((v1.y - mu) * rs * g1.y + b1.y);
    o1.z = f2bf((v1.z - mu) * rs * g1.z + b1.z);
    o1.w = f2bf((v1.w - mu) * rs * g1.w + b1.w);
    ushort4* op = (ushort4*)(out + (size_t)row * HH);
    op[t] = o0; op[t + 256] = o1;
}

// ---------------- reduce: out = sum(partials) + res + bias ----------------
template<int NP>
__global__ __launch_bounds__(256) void reduceN_kernel(
    const float* __restrict__ p0, const float* __restrict__ p1,
    const float* __restrict__ p2, const float* __restrict__ p3,
    const float* __restrict__ res, const float* __restrict__ bias,
    float* __restrict__ out, int n4, int nc4m1)
{
    int i = blockIdx.x * blockDim.x + threadIdx.x;
    int st = gridDim.x * blockDim.x;
    for (; i < n4; i += st) {
        float4 a = ((const float4*)p0)[i];
        float4 b = ((const float4*)p1)[i];
        float4 r = ((const float4*)res)[i];
        float4 bv = ((const float4*)bias)[i & nc4m1];
        float4 o;
        o.x = a.x + b.x + r.x + bv.x;
        o.y = a.y + b.y + r.y + bv.y;
        o.z = a.z + b.z + r.z + bv.z;
        o.w = a.w + b.w + r.w + bv.w;
        if (NP >= 3) {
            float4 c = ((const float4*)p2)[i];
            o.x += c.x; o.y += c.y; o.z += c.z; o.w += c.w;
        }
        if (NP >= 4) {
            float4 d = ((const float4*)p3)[i];
            o.x += d.x; o.y += d.y; o.z += d.z; o.w += d.w;
        }
        ((float4*)out)[i] = o;
    }
}

// =============== 256x256 2-section GEMM (counted-lgkm overlap) ===============
// C[M,N] = A[M,K]bf16 @ B[N,K]bf16^T. BK=64, 512 thr = 8 waves (2Mx4N),
// per-wave C 128x64. LDS 2buf x (A 256x64 + B 256x64), chunk-XOR swizzle.
// Per K-tile, TWO barrier sections; NO explicit lgkmcnt drain — every ds_read
// is consumed by an MFMA in its own section, so the compiler's counted
// lgkmcnt interleaves reads under the MFMA stream (the m97/m201 mechanism).
//   S_A: stage Ab,Bd(t1)->buf^1; read afT(8)+bL(4)+bR(4); 32 MFMA Q00+Q01; bar
//   S_B: stage Aa,Bg(t2)->buf;   read afB(8);             32 MFMA Q11+Q10;
//        vmcnt(4); bar
// Overwrite ledger (gld16 target vs last LDS-read of that region):
//   Ab(t1): read as afB in u-1 S_B, consumed pre-bar -> 1 bar gap. OK
//   Bd(t1): read as bR in u-1 S_A -> 2 bar gap. OK
//   Aa(t2): read as afT this tile S_A -> 1 bar gap. OK
//   Bg(t2): read as bL this tile S_A -> 1 bar gap. OK
// vmcnt(4) at S_B end completes Ab,Bd(t1) (and older) -> buf^1 ready.

__device__ __forceinline__ void stageA(unsigned short (*dst)[64],
    const unsigned short* Abase, int ld, int h, int wid, int lane)
{
    int rb = (wid >> 2) * 128 + h * 64 + (wid & 3) * 16;
    #pragma unroll
    for (int j = 0; j < 2; j++) {
        int r = rb + j * 8 + (lane >> 3);
        int ch = (lane & 7) ^ (r & 7);
        gld16(&dst[rb + j * 8][0], Abase + (size_t)r * ld + ch * 8);
    }
}

__device__ __forceinline__ void stageB(unsigned short (*dst)[64],
    const unsigned short* Bbase, int ld, int h, int wid, int lane)
{
    int rb = (wid >> 1) * 64 + h * 32 + (wid & 1) * 16;
    #pragma unroll
    for (int j = 0; j < 2; j++) {
        int r = rb + j * 8 + (lane >> 3);
        int ch = (lane & 7) ^ (r & 7);
        gld16(&dst[rb + j * 8][0], Bbase + (size_t)r * ld + ch * 8);
    }
}

__device__ __forceinline__ void loadA(const unsigned short (*ldsA)[64],
    bf16x8 (&af)[2][4], int half, int wr, int lo, int hi)
{
    #pragma unroll
    for (int ks = 0; ks < 2; ks++) {
        int g = ks * 4 + hi;
        #pragma unroll
        for (int i = 0; i < 4; i++) {
            int r = wr * 128 + half * 64 + i * 16 + lo;
            af[ks][i] = *(const bf16x8*)&ldsA[r][(g ^ (r & 7)) << 3];
        }
    }
}

__device__ __forceinline__ void loadB(const unsigned short (*ldsB)[64],
    bf16x8 (&bf)[2][2], int half, int wc, int lo, int hi)
{
    #pragma unroll
    for (int ks = 0; ks < 2; ks++) {
        int g = ks * 4 + hi;
        #pragma unroll
        for (int c = 0; c < 2; c++) {
            int r = wc * 64 + half * 32 + c * 16 + lo;
            bf[ks][c] = *(const bf16x8*)&ldsB[r][(g ^ (r & 7)) << 3];
        }
    }
}

template<int QR, int QC>
__device__ __forceinline__ void mfma16(
    const bf16x8 (&bf)[2][2], const bf16x8 (&af)[2][4], f32x4 (&acc)[8][4])
{
    #pragma unroll
    for (int ks = 0; ks < 2; ks++)
        #pragma unroll
        for (int i = 0; i < 4; i++)
            #pragma unroll
            for (int c = 0; c < 2; c++)
                acc[QR*4+i][QC*2+c] = __builtin_amdgcn_mfma_f32_16x16x32_bf16(
                    bf[ks][c], af[ks][i], acc[QR*4+i][QC*2+c], 0, 0, 0);
}

// MODE: 0 = fp32 partial (no bias), 1 = bf16 + bias (+GELU), 2 = QKV splitV
template<int MODE, int GELU_ON>
__global__ __launch_bounds__(512, 2) void gemm256(
    const unsigned short* __restrict__ A, const unsigned short* __restrict__ B,
    const float* __restrict__ bias, void* __restrict__ outp,
    unsigned short* __restrict__ vtb, void* __restrict__ outp_hi,
    int N, int lda, int ldb, int kLen, int Ktot, int CH, int CW)
{
    __shared__ unsigned short lds[2][2][256][64];   // 128 KiB

    int t = threadIdx.x, lane = t & 63, wid = t >> 6;
    int lo = lane & 15, hi = lane >> 4;
    int wr = wid >> 2, wc = wid & 3;

    // 2D chunked XCD swizzle over the (R = bz*gy+by, bx) tile grid.
    int id = (blockIdx.z * gridDim.y + blockIdx.y) * gridDim.x + blockIdx.x;
    int xcd = id & 7, local = id >> 3;
    int cgx = gridDim.x / CW;                 // chunk-grid cols
    int cr = xcd / cgx, cc = xcd - cr * cgx;  // chunk position
    int lr = local / CW, lc = local - lr * CW;
    int R  = cr * CH + lr;
    int bn = cc * CW + lc;
    int bm = R % gridDim.y;
    int bz = R / gridDim.y;
    int m0 = bm * 256, n0 = bn * 256;
    int kstart = bz * kLen;
    int rem = Ktot - kstart;
    int nt = ((rem < kLen) ? rem : kLen) >> 6;

    const unsigned short* At = A + (size_t)m0 * lda + kstart;
    const unsigned short* Bt = B + (size_t)n0 * ldb + kstart;

    // prologue: tile0 full + Aa(1), Bg(1); then vmcnt(4)
    stageA(lds[0][0], At, lda, 0, wid, lane);
    stageA(lds[0][0], At, lda, 1, wid, lane);
    stageB(lds[0][1], Bt, ldb, 0, wid, lane);
    stageB(lds[0][1], Bt, ldb, 1, wid, lane);
    int k1 = (nt > 1) ? 64 : 0;
    stageA(lds[1][0], At + k1, lda, 0, wid, lane);
    stageB(lds[1][1], Bt + k1, ldb, 0, wid, lane);
    asm volatile("s_waitcnt vmcnt(4)" ::: "memory");
    __builtin_amdgcn_s_barrier();

    f32x4 acc[8][4] = {};
    bf16x8 afT[2][4], afB[2][4], bL[2][2], bR[2][2];

    for (int u = 0; u < nt; u++) {
        int buf = u & 1;
        const unsigned short (*LA)[64] = lds[buf][0];
        const unsigned short (*LB)[64] = lds[buf][1];
        int t1 = (u + 1 < nt) ? u + 1 : nt - 1;
        int t2 = (u + 2 < nt) ? u + 2 : nt - 1;

        // ---- S_A: Q00 + Q01
        stageA(lds[buf ^ 1][0], At + t1 * 64, lda, 1, wid, lane);   // Ab(t1)
        stageB(lds[buf ^ 1][1], Bt + t1 * 64, ldb, 1, wid, lane);   // Bd(t1)
        __builtin_amdgcn_s_setprio(1);
        loadA(LA, afT, 0, wr, lo, hi);
        loadB(LB, bL, 0, wc, lo, hi);
        loadB(LB, bR, 1, wc, lo, hi);
        mfma16<0, 0>(bL, afT, acc);
        mfma16<0, 1>(bR, afT, acc);
        __builtin_amdgcn_s_setprio(0);
        __builtin_amdgcn_s_barrier();

        // ---- S_B: Q11 + Q10; counted vmcnt
        stageA(lds[buf][0], At + t2 * 64, lda, 0, wid, lane);       // Aa(t2)
        stageB(lds[buf][1], Bt + t2 * 64, ldb, 0, wid, lane);       // Bg(t2)
        __builtin_amdgcn_s_setprio(1);
        loadA(LA, afB, 1, wr, lo, hi);
        mfma16<1, 1>(bR, afB, acc);
        mfma16<1, 0>(bL, afB, acc);
        __builtin_amdgcn_s_setprio(0);
        asm volatile("s_waitcnt vmcnt(4)" ::: "memory");
        __builtin_amdgcn_s_barrier();
    }

    // ---- epilogue ----  acc[ri][ci][j]: row M = m0+wr*128+ri*16+lo,
    //                     col N = n0+wc*64+ci*16+hi*4+j  (j contiguous in N)
    if (MODE == 0) {
        float* po = (bz < 2)
            ? (float*)outp    + (size_t)bz       * SQ * (size_t)N
            : (float*)outp_hi + (size_t)(bz - 2) * SQ * (size_t)N;
        #pragma unroll
        for (int ri = 0; ri < 8; ri++) {
            int gr = m0 + wr * 128 + ri * 16 + lo;
            #pragma unroll
            for (int ci = 0; ci < 4; ci++) {
                int gc = n0 + wc * 64 + ci * 16 + hi * 4;
                *(f32x4*)&po[(size_t)gr * N + gc] = acc[ri][ci];
            }
        }
    } else if (MODE == 1) {
        unsigned short* op = (unsigned short*)outp;
        #pragma unroll
        for (int ri = 0; ri < 8; ri++) {
            int gr = m0 + wr * 128 + ri * 16 + lo;
            #pragma unroll
            for (int ci = 0; ci < 4; ci++) {
                int gc = n0 + wc * 64 + ci * 16 + hi * 4;
                float4 bi = *(const float4*)&bias[gc];
                float v0 = acc[ri][ci][0] + bi.x, v1 = acc[ri][ci][1] + bi.y;
                float v2 = acc[ri][ci][2] + bi.z, v3 = acc[ri][ci][3] + bi.w;
                if (GELU_ON) { v0 = gelu_f(v0); v1 = gelu_f(v1); v2 = gelu_f(v2); v3 = gelu_f(v3); }
                ushort4 o; o.x = f2bf(v0); o.y = f2bf(v1); o.z = f2bf(v2); o.w = f2bf(v3);
                *(ushort4*)&op[(size_t)gr * N + gc] = o;
            }
        }
    } else {
        unsigned short* op = (unsigned short*)outp;
        #pragma unroll
        for (int ri = 0; ri < 8; ri++) {
            int gr = m0 + wr * 128 + ri * 16 + lo;
            #pragma unroll
            for (int ci = 0; ci < 4; ci++) {
                int gc = n0 + wc * 64 + ci * 16 + hi * 4;
                int head = gc / 384;
                int within = gc - head * 384;
                float4 bi = *(const float4*)&bias[gc];
                float v0 = acc[ri][ci][0] + bi.x, v1 = acc[ri][ci][1] + bi.y;
                float v2 = acc[ri][ci][2] + bi.z, v3 = acc[ri][ci][3] + bi.w;
                if (within >= 256) {        // V columns -> transposed store
                    int d = within - 256;
                    unsigned short* vp = vtb + (size_t)(head * HD + d) * SQ + gr;
                    vp[0]          = f2bf(v0);
                    vp[SQ]         = f2bf(v1);
                    vp[2 * SQ]     = f2bf(v2);
                    vp[3 * SQ]     = f2bf(v3);
                } else {
                    ushort4 o; o.x = f2bf(v0); o.y = f2bf(v1); o.z = f2bf(v2); o.w = f2bf(v3);
                    *(ushort4*)&op[(size_t)gr * N + gc] = o;
                }
            }
        }
    }
}

// ---------------- Flash attention: 32x32 MFMA, causal + alibi ----------------
__global__ __launch_bounds__(128) void attn_kernel(
    const unsigned short* __restrict__ qkvB,  // [S][6144] bf16 (q,k valid)
    const unsigned short* __restrict__ vtb,   // [NH][HD][S] bf16
    unsigned short* __restrict__ ctx)         // [S][2048] bf16
{
    int w = blockIdx.x;
    int lid = (w & 7) * 64 + (w >> 3);
    int n = lid >> 5, qt = lid & 31;
    int t = threadIdx.x, lane = t & 63, wid = t >> 6;
    int l32 = lane & 31, h2 = lane >> 5;
    int q0 = qt * 64, qg = q0 + wid * 32 + l32;

    __shared__ __align__(16) unsigned short Ks[64][128];
    __shared__ __align__(16) unsigned short Vt[128][64];

    bf16x8 qf[8];
    const unsigned short* qp = qkvB + (size_t)qg * QKVW + n * 384 + h2 * 8;
    #pragma unroll
    for (int d8 = 0; d8 < 8; d8++)
        qf[d8] = *(const bf16x8*)(qp + d8 * 16);

    const float slope = exp2f(-0.5f * (float)(n + 1));
    const float inv = 0.08838834764831845f;   // 1/sqrt(128)
    float m = -INFINITY, lsum = 0.f;
    f32x16 ao[4] = {};

    int krow = lane >> 4, kch = lane & 15;
    int vrow = lane >> 3, vch = lane & 7;
    const unsigned short* kb_ = qkvB + n * 384 + 128;
    const unsigned short* vb_ = vtb + (size_t)n * HD * SQ;
    const char* ksb = (const char*)&Ks[0][0];
    const char* vsb = (const char*)&Vt[0][0];

    int nkb = qt + 1;
    for (int kb = 0; kb < nkb; kb++) {
        int k0 = kb * 64;
        __syncthreads();
        #pragma unroll
        for (int s = 0; s < 8; s++) {
            int r = wid * 32 + s * 4 + krow;
            gld16(&Ks[wid * 32 + s * 4][0],
                  kb_ + (size_t)(k0 + r) * QKVW + ((kch ^ (r & 7)) << 3));
            int dd = wid * 64 + s * 8 + vrow;
            gld16(&Vt[wid * 64 + s * 8][0],
                  vb_ + (size_t)dd * SQ + k0 + ((vch ^ (dd & 7)) << 3));
        }
        __syncthreads();

        f32x16 sc0 = {}, sc1 = {};
        #pragma unroll
        for (int d8 = 0; d8 < 8; d8++) {
            int ch = ((d8 * 2 + h2) ^ (l32 & 7)) << 4;
            bf16x8 kf0 = *(const bf16x8*)(ksb + l32 * 256 + ch);
            bf16x8 kf1 = *(const bf16x8*)(ksb + (32 + l32) * 256 + ch);
            sc0 = __builtin_amdgcn_mfma_f32_32x32x16_bf16(kf0, qf[d8], sc0, 0, 0, 0);
            sc1 = __builtin_amdgcn_mfma_f32_32x32x16_bf16(kf1, qf[d8], sc1, 0, 0, 0);
        }

        float tmax = -INFINITY;
        int last = (kb == nkb - 1);
        #pragma unroll
        for (int r = 0; r < 16; r++) {
            int kl = (r & 3) + 8 * (r >> 2) + 4 * h2;
            float s0 = sc0[r] * inv + slope * (float)(k0 + kl);
            float s1 = sc1[r] * inv + slope * (float)(k0 + 32 + kl);
            if (last) {
                if (k0 + kl > qg) s0 = -INFINITY;
                if (k0 + 32 + kl > qg) s1 = -INFINITY;
            }
            sc0[r] = s0; sc1[r] = s1;
            tmax = fmaxf(tmax, fmaxf(s0, s1));
        }
        tmax = fmaxf(tmax, __shfl_xor(tmax, 32));
        if (!__all(tmax <= m + 8.f)) {          // defer-max (T13)
            float mnew = fmaxf(m, tmax);
            float sca = __expf(m - mnew);
            m = mnew;
            lsum *= sca;
            #pragma unroll
            for (int db = 0; db < 4; db++)
                #pragma unroll
                for (int e = 0; e < 16; e++) ao[db][e] *= sca;
        }
        float psum = 0.f;
        #pragma unroll
        for (int r = 0; r < 16; r++) {
            sc0[r] = __expf(sc0[r] - m); psum += sc0[r];
            sc1[r] = __expf(sc1[r] - m); psum += sc1[r];
        }
        psum += __shfl_xor(psum, 32);
        lsum += psum;

        #pragma unroll
        for (int kstep = 0; kstep < 4; kstep++) {
            const int ks1 = kstep & 1;
            float a0, a1, a2, a3, b0, b1, b2, b3;
            if (kstep < 2) {
                a0 = sc0[8*ks1+0]; a1 = sc0[8*ks1+1]; a2 = sc0[8*ks1+2]; a3 = sc0[8*ks1+3];
                b0 = sc0[8*ks1+4]; b1 = sc0[8*ks1+5]; b2 = sc0[8*ks1+6]; b3 = sc0[8*ks1+7];
            } else {
                a0 = sc1[8*ks1+0]; a1 = sc1[8*ks1+1]; a2 = sc1[8*ks1+2]; a3 = sc1[8*ks1+3];
                b0 = sc1[8*ks1+4]; b1 = sc1[8*ks1+5]; b2 = sc1[8*ks1+6]; b3 = sc1[8*ks1+7];
            }
            unsigned ku0 = pack_bf2(h2 ? b0 : a0, h2 ? b1 : a1);
            unsigned ku1 = pack_bf2(h2 ? b2 : a2, h2 ? b3 : a3);
            unsigned su0 = pack_bf2(h2 ? a0 : b0, h2 ? a1 : b1);
            unsigned su1 = pack_bf2(h2 ? a2 : b2, h2 ? a3 : b3);
            unsigned r0 = (unsigned)__shfl_xor((int)su0, 32);
            unsigned r1 = (unsigned)__shfl_xor((int)su1, 32);
            union { int4 i; bf16x8 v; } u;
            u.i.x = h2 ? (int)r0  : (int)ku0;
            u.i.y = h2 ? (int)r1  : (int)ku1;
            u.i.z = h2 ? (int)ku0 : (int)r0;
            u.i.w = h2 ? (int)ku1 : (int)r1;
            bf16x8 pf = u.v;
            int ch = ((kstep * 2 + h2) ^ (l32 & 7)) << 4;
            #pragma unroll
            for (int db = 0; db < 4; db++) {
                bf16x8 vf = *(const bf16x8*)(vsb + (db * 32 + l32) * 128 + ch);
                ao[db] = __builtin_amdgcn_mfma_f32_32x32x16_bf16(vf, pf, ao[db], 0, 0, 0);
            }
        }
    }

    float rl = 1.f / lsum;
    #pragma unroll
    for (int db = 0; db < 4; db++)
        #pragma unroll
        for (int g = 0; g < 4; g++) {
            ushort4 o;
            o.x = f2bf(ao[db][g*4+0] * rl);
            o.y = f2bf(ao[db][g*4+1] * rl);
            o.z = f2bf(ao[db][g*4+2] * rl);
            o.w = f2bf(ao[db][g*4+3] * rl);
            *(ushort4*)(ctx + (size_t)qg * HH + n * HD + db * 32 + g * 8 + h2 * 4) = o;
        }
}

extern "C" void kernel_launch(void* const* d_in, const int* in_sizes, int n_in,
                              void* d_out, int out_size, void* d_ws, size_t ws_size,
                              hipStream_t stream) {
    const float* hs    = (const float*)d_in[0];
    const float* ln1g  = (const float*)d_in[4];
    const float* ln1b  = (const float*)d_in[5];
    const float* qkvw  = (const float*)d_in[6];
    const float* qkvb  = (const float*)d_in[7];
    const float* dw    = (const float*)d_in[8];
    const float* db    = (const float*)d_in[9];
    const float* ln2g  = (const float*)d_in[10];
    const float* ln2b  = (const float*)d_in[11];
    const float* f1w   = (const float*)d_in[12];
    const float* f1b   = (const float*)d_in[13];
    const float* f2w   = (const float*)d_in[14];
    const float* f2b   = (const float*)d_in[15];
    float* out = (float*)d_out;

    char* ws = (char*)d_ws;
    size_t off = 0;
    auto alloc = [&](size_t nbytes) {
        void* p = ws + off; off += (nbytes + 255) & ~(size_t)255; return p;
    };
    unsigned short* xbf  = (unsigned short*)alloc((size_t)SQ * HH * 2);        // [0, 8.4M)
    unsigned short* qkvB = (unsigned short*)alloc((size_t)SQ * QKVW * 2);      // [8.4M, 33.6M)
    unsigned short* vtB  = (unsigned short*)alloc((size_t)NHEAD * HD * SQ * 2);// [33.6M, 41.9M)
    unsigned short* ctx  = (unsigned short*)alloc((size_t)SQ * HH * 2);        // [41.9M, 50.3M)
    float*          attn = (float*)alloc((size_t)SQ * HH * 4);                 // [50.3M, 67.1M)
    unsigned short* y    = (unsigned short*)alloc((size_t)SQ * HH * 2);        // [67.1M, 75.5M)
    unsigned short* hdn  = (unsigned short*)alloc((size_t)SQ * 4 * HH * 2);    // [75.5M, 109.1M)
    unsigned short* wbuf = (unsigned short*)alloc((size_t)4 * HH * HH * 2);    // [109.1M, 142.6M)

    const size_t PQ = (size_t)SQ * HH;      // floats per partial (16.8 MB)
    float* part = (float*)ws;               // partials 0..2 overlap dead xbf/qkvB/vtB/ctx

    ln_kernel<<<SQ, 256, 0, stream>>>(hs, ln1g, ln1b, xbf);

    cvt_kernel<<<2048, 256, 0, stream>>>(qkvw, wbuf, QKVW * HH / 4);
    gemm256<2, 0><<<dim3(QKVW / 256, SQ / 256, 1), 512, 0, stream>>>(
        xbf, wbuf, qkvb, qkvB, vtB, nullptr, QKVW, HH, HH, HH, HH, 4, 6);

    attn_kernel<<<512, 128, 0, stream>>>(qkvB, vtB, ctx);

    // dense: split-K x4 (256 blocks); partials p0,p1 at ws; p2,p3 in dead hdn
    cvt_kernel<<<1024, 256, 0, stream>>>(dw, wbuf, HH * HH / 4);
    gemm256<0, 0><<<dim3(HH / 256, SQ / 256, 4), 512, 0, stream>>>(
        ctx, wbuf, nullptr, part, nullptr, hdn, HH, HH, HH, HH / 4, HH, 8, 4);
    reduceN_kernel<4><<<2048, 256, 0, stream>>>(
        part, part + PQ, (float*)hdn, (float*)hdn + PQ, hs, db, attn, SQ * HH / 4, HH / 4 - 1);

    ln_kernel<<<SQ, 256, 0, stream>>>(attn, ln2g, ln2b, y);

    cvt_kernel<<<2048, 256, 0, stream>>>(f1w, wbuf, 4 * HH * HH / 4);
    gemm256<1, 1><<<dim3(4 * HH / 256, SQ / 256, 1), 512, 0, stream>>>(
        y, wbuf, f1b, hdn, nullptr, nullptr, 4 * HH, HH, HH, HH, HH, 4, 8);

    // FC2: split-K x3 (192 blocks, kLen=2752=43 tiles); partials at ws[0,50.3M)
    cvt_kernel<<<2048, 256, 0, stream>>>(f2w, wbuf, 4 * HH * HH / 4);
    gemm256<0, 0><<<dim3(HH / 256, SQ / 256, 3), 512, 0, stream>>>(
        hdn, wbuf, nullptr, part, nullptr, part + 2 * PQ, HH, 4 * HH, 4 * HH, 2752, 4 * HH, 6, 4);
    reduceN_kernel<3><<<2048, 256, 0, stream>>>(
        part, part + PQ, part + 2 * PQ, nullptr, attn, f2b, out, SQ * HH / 4, HH / 4 - 1);
}